// Round 6
// baseline (1168.987 us; speedup 1.0000x reference)
//
#include <hip/hip_runtime.h>
#include <hip/hip_bf16.h>

// Sizes (fixed per problem)
#define Bz 64
#define Sz 256
#define Ez 256
#define Hz 256
#define Lz 1024
#define VLz 16

// split-precision scale: x stored as hi+lo of (x*SCL); products carry SCL^2
#define SCL 64.0f
#define DESCL (1.0f / 4096.0f)

typedef _Float16 half2_t __attribute__((ext_vector_type(2)));
typedef _Float16 half4_t __attribute__((ext_vector_type(4)));
typedef _Float16 f16x8   __attribute__((ext_vector_type(8)));
typedef float    f32x4   __attribute__((ext_vector_type(4)));

__device__ inline float fdot2(half2_t a, half2_t b, float c) {
#if __has_builtin(__builtin_amdgcn_fdot2)
    return __builtin_amdgcn_fdot2(a, b, c, false);
#else
    return c + (float)a[0] * (float)b[0] + (float)a[1] * (float)b[1];
#endif
}

// async global->LDS 16B; LDS dest must be linear lane-ordered (m104/m173)
__device__ inline void stage16(_Float16* ldst, const _Float16* gsrc) {
#if __has_builtin(__builtin_amdgcn_global_load_lds)
    __builtin_amdgcn_global_load_lds(
        (const __attribute__((address_space(1))) unsigned int*)gsrc,
        (__attribute__((address_space(3))) unsigned int*)ldst, 16, 0, 0);
#else
    *(f16x8*)ldst = *(const f16x8*)gsrc;
#endif
}

// ---------------------------------------------------------------------------
// K1: Vsum[l,e] = sum_j emb[V_idx[l,j], e]; norms; hi/lo split copy
__global__ void vsum_kernel(const int* __restrict__ V_idx, const float* __restrict__ emb,
                            float* __restrict__ Vsum, _Float16* __restrict__ vsh,
                            _Float16* __restrict__ vsl, float* __restrict__ vnorm)
{
    int l = blockIdx.x, e = threadIdx.x;
    float s = 0.f;
#pragma unroll
    for (int j = 0; j < VLz; ++j) {
        int idx = V_idx[l * VLz + j];
        s += emb[(long)idx * Ez + e];
    }
    Vsum[l * Ez + e] = s;
    float t = s * SCL;
    _Float16 h = (_Float16)t;
    vsh[l * Ez + e] = h;
    vsl[l * Ez + e] = (_Float16)(t - (float)h);
    __shared__ float red[256];
    red[e] = s * s; __syncthreads();
    for (int off = 128; off > 0; off >>= 1) { if (e < off) red[e] += red[e + off]; __syncthreads(); }
    if (e == 0) vnorm[l] = sqrtf(red[0]);
}

// K2: xe gather, hi/lo
__global__ void xe_kernel(const int* __restrict__ x, const float* __restrict__ emb,
                          _Float16* __restrict__ xeh, _Float16* __restrict__ xel)
{
    int i = blockIdx.x;              // b*S+s
    int e = threadIdx.x;
    float v = emb[(long)x[i] * Ez + e] * SCL;
    _Float16 h = (_Float16)v;
    xeh[(long)i * Ez + e] = h;
    xel[(long)i * Ez + e] = (_Float16)(v - (float)h);
}

// K3: pack w_hh [768,256] fp32 -> f16x2 for the Q=1 GRU.
// out index i = (kd*3+g)*256 + t  holds (w[g*256+t][2kd], w[g*256+t][2kd+1])
__global__ void wpack_kernel(const float* __restrict__ w_f, const float* __restrict__ w_b,
                             half2_t* __restrict__ out_f, half2_t* __restrict__ out_b)
{
    int i = blockIdx.x * 256 + threadIdx.x;   // 0 .. 98303
    int t = i & 255;
    int m = i >> 8;             // kd*3+g, 0..383
    int g = m % 3;
    int kd = m / 3;
    int o = g * 256 + t;
    int k = kd * 2;
    out_f[i] = half2_t{(_Float16)w_f[o * 256 + k], (_Float16)w_f[o * 256 + k + 1]};
    out_b[i] = half2_t{(_Float16)w_b[o * 256 + k], (_Float16)w_b[o * 256 + k + 1]};
}

// f32 -> scaled hi/lo f16
__global__ void cvtsplit_kernel(const float* __restrict__ in, _Float16* __restrict__ hi,
                                _Float16* __restrict__ lo, int n)
{
    int i = blockIdx.x * 256 + threadIdx.x;
    if (i < n) {
        float v = in[i] * SCL;
        _Float16 h = (_Float16)v;
        hi[i] = h;
        lo[i] = (_Float16)(v - (float)h);
    }
}

// ---------------------------------------------------------------------------
// Split-precision MFMA NT GEMM: C = (1/4096)*(Ah+Al)@(Bh+Bl)^T (+bias)(+epi).
// acc = Ah*Bh + Ah*Bl (+ Al*Bh if SPLIT_A). BM=BN=128, BK=32, 4 waves 2x2.
// OUTM: 0 = f32 C, 1 = scaled hi/lo f16 (Ch,Cl), 2 = scaled hi f16 only.
template<int EPI, int BIAS, int OUTM, int SPLIT_A>
__global__ __launch_bounds__(256, 2) void gemm_mfma(
    const _Float16* __restrict__ Ah, const _Float16* __restrict__ Al,
    const _Float16* __restrict__ Bh, const _Float16* __restrict__ Bl,
    const float* __restrict__ bias, float* __restrict__ C,
    _Float16* __restrict__ Ch, _Float16* __restrict__ Cl,
    int M, int N, int K, long sA, long sB, long sC)
{
    int bz = blockIdx.z;
    Ah += (long)bz * sA;
    if (SPLIT_A) Al += (long)bz * sA;
    Bh += (long)bz * sB;
    Bl += (long)bz * sB;
    __shared__ __attribute__((aligned(16))) _Float16 Ash[128 * 32];
    __shared__ __attribute__((aligned(16))) _Float16 Asl[128 * 32];
    __shared__ __attribute__((aligned(16))) _Float16 Bsh[128 * 32];
    __shared__ __attribute__((aligned(16))) _Float16 Bsl[128 * 32];
    int tid = threadIdx.x;
    int lane = tid & 63;
    int wid = tid >> 6;
    int wm = wid >> 1, wn = wid & 1;
    int m0 = blockIdx.y * 128, n0 = blockIdx.x * 128;

    // staging: thread -> (row = tid>>2, slot = tid&3); source chunk XOR-swizzled
    int srow = tid >> 2, sslot = tid & 3;
    int sw0 = sslot ^ ((srow >> 1) & 3);          // invariant under row+64
    long a0 = (long)(m0 + srow) * K + sw0 * 8;
    long a1 = (long)(m0 + 64 + srow) * K + sw0 * 8;
    long b0 = (long)(n0 + srow) * K + sw0 * 8;
    long b1 = (long)(n0 + 64 + srow) * K + sw0 * 8;

    f32x4 acc[4][4] = {};
    int r16 = lane & 15, kg = lane >> 4;

    for (int k0 = 0; k0 < K; k0 += 32) {
        stage16(&Ash[tid * 8],        Ah + a0 + k0);
        stage16(&Ash[2048 + tid * 8], Ah + a1 + k0);
        if (SPLIT_A) {
            stage16(&Asl[tid * 8],        Al + a0 + k0);
            stage16(&Asl[2048 + tid * 8], Al + a1 + k0);
        }
        stage16(&Bsh[tid * 8],        Bh + b0 + k0);
        stage16(&Bsh[2048 + tid * 8], Bh + b1 + k0);
        stage16(&Bsl[tid * 8],        Bl + b0 + k0);
        stage16(&Bsl[2048 + tid * 8], Bl + b1 + k0);
        __syncthreads();
        f16x8 afh[4], afl[4], bfh[4], bfl[4];
#pragma unroll
        for (int mi = 0; mi < 4; ++mi) {
            int r = wm * 64 + mi * 16 + r16;
            int sl = kg ^ ((r >> 1) & 3);
            int off = r * 32 + sl * 8;
            afh[mi] = *(const f16x8*)&Ash[off];
            if (SPLIT_A) afl[mi] = *(const f16x8*)&Asl[off];
        }
#pragma unroll
        for (int ni = 0; ni < 4; ++ni) {
            int n = wn * 64 + ni * 16 + r16;
            int sl = kg ^ ((n >> 1) & 3);
            int off = n * 32 + sl * 8;
            bfh[ni] = *(const f16x8*)&Bsh[off];
            bfl[ni] = *(const f16x8*)&Bsl[off];
        }
#pragma unroll
        for (int mi = 0; mi < 4; ++mi)
#pragma unroll
            for (int ni = 0; ni < 4; ++ni) {
                acc[mi][ni] = __builtin_amdgcn_mfma_f32_16x16x32_f16(afh[mi], bfh[ni], acc[mi][ni], 0, 0, 0);
                acc[mi][ni] = __builtin_amdgcn_mfma_f32_16x16x32_f16(afh[mi], bfl[ni], acc[mi][ni], 0, 0, 0);
                if (SPLIT_A)
                    acc[mi][ni] = __builtin_amdgcn_mfma_f32_16x16x32_f16(afl[mi], bfh[ni], acc[mi][ni], 0, 0, 0);
            }
        __syncthreads();
    }

    long coff = (long)bz * sC;
#pragma unroll
    for (int mi = 0; mi < 4; ++mi) {
#pragma unroll
        for (int ni = 0; ni < 4; ++ni) {
            int n = n0 + wn * 64 + ni * 16 + r16;
            float bv = BIAS ? bias[n] : 0.f;
#pragma unroll
            for (int j = 0; j < 4; ++j) {
                int m = m0 + wm * 64 + mi * 16 + kg * 4 + j;
                float v = acc[mi][ni][j] * DESCL + bv;
                if (EPI == 1) v = fmaxf(v, 0.f);
                if (EPI == 2) v = tanhf(v);
                long idx = coff + (long)m * N + n;
                if (OUTM == 0) {
                    C[idx] = v;
                } else if (OUTM == 1) {
                    float t = v * SCL;
                    _Float16 h = (_Float16)t;
                    Ch[idx] = h;
                    Cl[idx] = (_Float16)(t - (float)h);
                } else {
                    Ch[idx] = (_Float16)(v * SCL);
                }
            }
        }
    }
}

// ---------------------------------------------------------------------------
// K4: GRU recurrence, Q=1 layout. One block per (dir,batch), 256 threads =
// 4 waves = 1 wave/SIMD at 1 block/CU. Thread t owns output t and ALL 256 k:
// 384 half2 weight dwords register-resident under the 512-VGPR budget of
// __launch_bounds__(256,1). (Rounds 4/5 proved tighter caps spill: the
// allocator dumped a 192-reg array to scratch at cap 256 -> L2-roofline
// 361-398us.) No cross-thread reduction; double-buffered h; ONE barrier/step;
// gx prefetched one step ahead.
__global__ __launch_bounds__(256, 1) void gru_kernel(
    const float* __restrict__ gx_f, const float* __restrict__ gx_b,
    const half2_t* __restrict__ wq_f, const half2_t* __restrict__ wq_b,
    const float* __restrict__ bhh_f, const float* __restrict__ bhh_b,
    _Float16* __restrict__ dh_out, _Float16* __restrict__ dl_out)
{
    int dir = blockIdx.x >> 6;
    int b   = blockIdx.x & 63;
    const float*   gx  = dir ? gx_b : gx_f;
    const half2_t* wq  = dir ? wq_b : wq_f;
    const float*   bhh = dir ? bhh_b : bhh_f;
    int t = threadIdx.x;

    __shared__ __attribute__((aligned(16))) _Float16 hbuf[2][256];

    half2_t wr[384];
    const half2_t* wbase = wq + t;
#pragma unroll
    for (int m = 0; m < 384; ++m) wr[m] = wbase[m << 8];
    // Opaque pin: forbid re-load rematerialization inside the step loop.
#pragma unroll
    for (int m = 0; m < 384; ++m) asm volatile("" : "+v"(wr[m]));

    float br = bhh[t], bz = bhh[256 + t], bn = bhh[512 + t];
    float hprev = 0.f;
    hbuf[0][t] = (_Float16)0.f;
    __syncthreads();

    // prefetch step 0 gate-x
    float xr, xz, xn;
    {
        int s0 = dir ? (Sz - 1) : 0;
        const float* g0 = gx + (size_t)(b * Sz + s0) * 768;
        xr = g0[t]; xz = g0[256 + t]; xn = g0[512 + t];
    }

    for (int step = 0; step < Sz; ++step) {
        int s = dir ? (Sz - 1 - step) : step;
        // issue next step's gx loads early (hidden under the dot phase)
        float nxr = 0.f, nxz = 0.f, nxn = 0.f;
        if (step + 1 < Sz) {
            int sn = dir ? (Sz - 2 - step) : (step + 1);
            const float* gn = gx + (size_t)(b * Sz + sn) * 768;
            nxr = gn[t]; nxz = gn[256 + t]; nxn = gn[512 + t];
        }

        float ar = 0.f, az = 0.f, an = 0.f;
        const f16x8* hp8 = (const f16x8*)hbuf[step & 1];
#pragma unroll
        for (int c = 0; c < 32; ++c) {
            f16x8 hv = hp8[c];     // uniform-address broadcast read
#pragma unroll
            for (int j = 0; j < 4; ++j) {
                half2_t hj = {hv[2 * j], hv[2 * j + 1]};
                int kd = c * 4 + j;
                ar = fdot2(wr[kd * 3 + 0], hj, ar);
                az = fdot2(wr[kd * 3 + 1], hj, az);
                an = fdot2(wr[kd * 3 + 2], hj, an);
            }
        }

        float r  = 1.f / (1.f + expf(-(xr + br + ar)));
        float z  = 1.f / (1.f + expf(-(xz + bz + az)));
        float nn = tanhf(xn + r * (an + bn));
        float hnew = (1.f - z) * nn + z * hprev;

        float hscl = hnew * SCL;
        _Float16 hh = (_Float16)hscl;
        size_t idx = (size_t)(b * Sz + s) * 512 + dir * 256 + t;
        dh_out[idx] = hh;
        dl_out[idx] = (_Float16)(hscl - (float)hh);

        hbuf[(step + 1) & 1][t] = (_Float16)hnew;
        hprev = hnew;
        xr = nxr; xz = nxz; xn = nxn;
        __syncthreads();
    }
}

// ---------------------------------------------------------------------------
// transpose d (hi,lo) [B*S][512] -> dT (hi,lo) [B][512][256]
__global__ __launch_bounds__(256) void dtrans_kernel(
    const _Float16* __restrict__ dh, const _Float16* __restrict__ dl,
    _Float16* __restrict__ dTh, _Float16* __restrict__ dTl)
{
    __shared__ _Float16 th[64][68];
    __shared__ _Float16 tl[64][68];
    int s0 = blockIdx.x << 6;
    int h0 = blockIdx.y << 6;
    int b  = blockIdx.z;
    int tid = threadIdx.x;
#pragma unroll
    for (int i = 0; i < 16; ++i) {
        int idx = tid + i * 256;
        int s = idx >> 6, h = idx & 63;
        size_t gi = (size_t)(b * 256 + s0 + s) * 512 + h0 + h;
        th[s][h] = dh[gi];
        tl[s][h] = dl[gi];
    }
    __syncthreads();
#pragma unroll
    for (int i = 0; i < 16; ++i) {
        int idx = tid + i * 256;
        int h = idx >> 6, s = idx & 63;
        size_t gi = (size_t)(b * 512 + h0 + h) * 256 + s0 + s;
        dTh[gi] = th[s][h];
        dTl[gi] = tl[s][h];
    }
}

// ---------------------------------------------------------------------------
// BN stats over (b, e) for each channel c (layout y[b][CH][256])
__global__ void bn_stats_kernel(const float* __restrict__ y, int CH,
                                float* __restrict__ mean, float* __restrict__ istd)
{
    int c = blockIdx.x, t = threadIdx.x;
    float s = 0.f, ss = 0.f;
    for (int b = 0; b < Bz; ++b) {
        float v = y[((long)b * CH + c) * 256 + t];
        s += v; ss += v * v;
    }
    __shared__ float rs[256], rss[256];
    rs[t] = s; rss[t] = ss; __syncthreads();
    for (int off = 128; off > 0; off >>= 1) {
        if (t < off) { rs[t] += rs[t + off]; rss[t] += rss[t + off]; }
        __syncthreads();
    }
    if (t == 0) {
        float cnt = (float)(Bz * 256);
        float m = rs[0] / cnt;
        float var = rss[0] / cnt - m * m;
        mean[c] = m;
        istd[c] = rsqrtf(var + 1e-5f);
    }
}

// BN apply + activation. HL=1: write scaled hi/lo f16; HL=0: in-place f32.
template<int EPI, int HL>
__global__ void bn_apply_kernel(float* __restrict__ y, _Float16* __restrict__ yh,
                                _Float16* __restrict__ yl, int CH,
                                const float* __restrict__ mean, const float* __restrict__ istd,
                                const float* __restrict__ g, const float* __restrict__ be)
{
    long i = (long)blockIdx.x * 256 + threadIdx.x;
    int c = (int)((i >> 8) % CH);
    float v = (y[i] - mean[c]) * istd[c] * g[c] + be[c];
    v = (EPI == 1) ? fmaxf(v, 0.f) : tanhf(v);
    if (HL) {
        float t = v * SCL;
        _Float16 h = (_Float16)t;
        yh[i] = h;
        yl[i] = (_Float16)(t - (float)h);
    } else {
        y[i] = v;
    }
}

// ---------------------------------------------------------------------------
// Output: cosine similarity * 10
__global__ void out_kernel(const float* __restrict__ e, const float* __restrict__ Vsum,
                           const float* __restrict__ vnorm, float* __restrict__ out)
{
    int bl = blockIdx.x;
    int l = bl & (Lz - 1);
    int t = threadIdx.x;
    float ev = e[(long)bl * 256 + t];
    float vv = Vsum[l * 256 + t];
    __shared__ float rd[256], rn[256];
    rd[t] = ev * vv; rn[t] = ev * ev; __syncthreads();
    for (int off = 128; off > 0; off >>= 1) {
        if (t < off) { rd[t] += rd[t + off]; rn[t] += rn[t + off]; }
        __syncthreads();
    }
    if (t == 0) {
        float num = rd[0];
        float den = fmaxf(sqrtf(rn[0]), 1e-8f) * fmaxf(vnorm[l], 1e-8f);
        out[bl] = num / den * 10.f;
    }
}

// ---------------------------------------------------------------------------
extern "C" void kernel_launch(void* const* d_in, const int* in_sizes, int n_in,
                              void* d_out, int out_size, void* d_ws, size_t ws_size,
                              hipStream_t stream)
{
    const int*   x      = (const int*)d_in[0];
    const int*   V_idx  = (const int*)d_in[1];
    const float* emb    = (const float*)d_in[2];
    const float* w_ih_f = (const float*)d_in[3];
    const float* w_hh_f = (const float*)d_in[4];
    const float* b_ih_f = (const float*)d_in[5];
    const float* b_hh_f = (const float*)d_in[6];
    const float* w_ih_b = (const float*)d_in[7];
    const float* w_hh_b = (const float*)d_in[8];
    const float* b_ih_b = (const float*)d_in[9];
    const float* b_hh_b = (const float*)d_in[10];
    const float* w1     = (const float*)d_in[11];
    const float* b1     = (const float*)d_in[12];
    const float* w2     = (const float*)d_in[13];
    const float* b2     = (const float*)d_in[14];
    const float* g1     = (const float*)d_in[15];
    const float* be1    = (const float*)d_in[16];
    const float* g2     = (const float*)d_in[17];
    const float* be2    = (const float*)d_in[18];

    float* ws = (float*)d_ws;
    float* out = (float*)d_out;

    // ---- workspace layout (float units); total 51,710,976 fl = 207 MB ----
    float*    vsum   = ws;                               // 262144
    float*    vnorm  = ws + 262144;                      // 1024
    float*    mean   = ws + 263168;                      // 1024
    float*    istd   = ws + 264192;                      // 1024
    half2_t*  wqf    = (half2_t*)(ws + 265216);          // 98304
    half2_t*  wqb    = (half2_t*)(ws + 363520);          // 98304
    _Float16* vsh    = (_Float16*)(ws + 461824);         // 131072 fl
    _Float16* vsl    = (_Float16*)(ws + 592896);         // 131072 fl
    _Float16* wihh_f = (_Float16*)(ws + 723968);         // 98304 fl
    _Float16* wihl_f = (_Float16*)(ws + 822272);         // 98304 fl
    _Float16* wihh_b = (_Float16*)(ws + 920576);         // 98304 fl
    _Float16* wihl_b = (_Float16*)(ws + 1018880);        // 98304 fl
    _Float16* w1h    = (_Float16*)(ws + 1117184);        // 65536 fl
    _Float16* w1l    = (_Float16*)(ws + 1182720);        // 65536 fl
    _Float16* w2h    = (_Float16*)(ws + 1248256);        // 65536 fl
    _Float16* w2l    = (_Float16*)(ws + 1313792);        // 65536 fl
    float*    AB     = ws + 1379328;                     // overlay arena
    // arena overlays (liveness-checked):
    _Float16* xeh    = (_Float16*)(AB + 0);              // st1-2
    _Float16* xel    = (_Float16*)(AB + 2097152);
    float*    gxf    = AB + 4194304;                     // st2-3
    float*    gxb    = AB + 16777216;
    _Float16* dh     = (_Float16*)(AB + 29360128);       // st3-4 (+dtrans)
    _Float16* dl     = (_Float16*)(AB + 33554432);
    _Float16* dTh    = (_Float16*)(AB + 0);              // dtrans-st6 (xe/gx dead)
    _Float16* dTl    = (_Float16*)(AB + 4194304);
    float*    d2pre  = AB + 8388608;                     // st4 (gx dead)
    _Float16* d2h    = (_Float16*)(AB + 12582912);       // st4-5
    _Float16* d2l    = (_Float16*)(AB + 14680064);
    _Float16* ah     = (_Float16*)(AB + 16777216);       // st5-6 (gxb/d dead)
    _Float16* al     = (_Float16*)(AB + 25165824);
    _Float16* c16    = (_Float16*)(AB + 33554432);       // st6-7 (dl dead)
    float*    epre   = AB + 0;                           // st7-8 (dT/d2 dead)

    // Stage 1: gathers + packs
    vsum_kernel<<<Lz, 256, 0, stream>>>(V_idx, emb, vsum, vsh, vsl, vnorm);
    xe_kernel<<<Bz * Sz, 256, 0, stream>>>(x, emb, xeh, xel);
    wpack_kernel<<<384, 256, 0, stream>>>(w_hh_f, w_hh_b, wqf, wqb);
    cvtsplit_kernel<<<768, 256, 0, stream>>>(w_ih_f, wihh_f, wihl_f, 196608);
    cvtsplit_kernel<<<768, 256, 0, stream>>>(w_ih_b, wihh_b, wihl_b, 196608);
    cvtsplit_kernel<<<512, 256, 0, stream>>>(w1, w1h, w1l, 131072);
    cvtsplit_kernel<<<512, 256, 0, stream>>>(w2, w2h, w2l, 131072);

    // Stage 2: gx = xe @ w_ih^T + b_ih  (M=16384, N=768, K=256), f32 out
    gemm_mfma<0, 1, 0, 1><<<dim3(6, 128, 1), 256, 0, stream>>>(
        xeh, xel, wihh_f, wihl_f, b_ih_f, gxf, nullptr, nullptr, Bz * Sz, 768, Ez, 0, 0, 0);
    gemm_mfma<0, 1, 0, 1><<<dim3(6, 128, 1), 256, 0, stream>>>(
        xeh, xel, wihh_b, wihl_b, b_ih_b, gxb, nullptr, nullptr, Bz * Sz, 768, Ez, 0, 0, 0);

    // Stage 3: GRU recurrence -> d hi/lo [B,S,512]; transpose -> dT [B,512,256]
    gru_kernel<<<128, 256, 0, stream>>>(gxf, gxb, wqf, wqb, b_hh_f, b_hh_b, dh, dl);
    dtrans_kernel<<<dim3(4, 8, Bz), 256, 0, stream>>>(dh, dl, dTh, dTl);

    // Stage 4: d2pre = d @ w1^T + b1 (M=16384, N=256, K=512) f32; BN1+relu -> hi/lo
    gemm_mfma<0, 1, 0, 1><<<dim3(2, 128, 1), 256, 0, stream>>>(
        dh, dl, w1h, w1l, b1, d2pre, nullptr, nullptr, Bz * Sz, Ez, 512, 0, 0, 0);
    bn_stats_kernel<<<Sz, 256, 0, stream>>>(d2pre, Sz, mean, istd);
    bn_apply_kernel<1, 1><<<Bz * Sz, 256, 0, stream>>>(d2pre, d2h, d2l, Sz, mean, istd, g1, be1);

    // Stage 5: a[b] = tanh(Vsum @ d2[b]^T)  (M=1024, N=256, K=256) -> hi/lo
    gemm_mfma<2, 0, 1, 1><<<dim3(2, 8, Bz), 256, 0, stream>>>(
        vsh, vsl, d2h, d2l, nullptr, nullptr, ah, al, Lz, Sz, Ez, 0, (long)Sz * Ez, (long)Lz * Sz);

    // Stage 6: c[b] = relu(a[b] @ dT[b]^T)  (M=1024, N=512, K=256) -> hi only
    gemm_mfma<1, 0, 2, 1><<<dim3(4, 8, Bz), 256, 0, stream>>>(
        ah, al, dTh, dTl, nullptr, nullptr, c16, nullptr, Lz, 512, Sz,
        (long)Lz * Sz, (long)512 * Sz, (long)Lz * 512);

    // Stage 7: epre = c @ w2^T + b2 (M=65536, N=256, K=512, A hi-only) f32; BN2+tanh
    gemm_mfma<0, 1, 0, 0><<<dim3(2, 512, 1), 256, 0, stream>>>(
        c16, nullptr, w2h, w2l, b2, epre, nullptr, nullptr, Bz * Lz, Ez, 512, 0, 0, 0);
    bn_stats_kernel<<<Lz, 256, 0, stream>>>(epre, Lz, mean, istd);
    bn_apply_kernel<2, 0><<<Bz * Lz, 256, 0, stream>>>(epre, nullptr, nullptr, Lz, mean, istd, g2, be2);

    // Stage 8: output
    out_kernel<<<Bz * Lz, 256, 0, stream>>>(epre, vsum, vnorm, out);
}

// Round 7
// 1113.307 us; speedup vs baseline: 1.0500x; 1.0500x over previous
//
#include <hip/hip_runtime.h>
#include <hip/hip_bf16.h>

// Sizes (fixed per problem)
#define Bz 64
#define Sz 256
#define Ez 256
#define Hz 256
#define Lz 1024
#define VLz 16

// split-precision scale: x stored as hi+lo of (x*SCL); products carry SCL^2
#define SCL 64.0f
#define DESCL (1.0f / 4096.0f)

typedef _Float16 half2_t __attribute__((ext_vector_type(2)));
typedef _Float16 f16x4   __attribute__((ext_vector_type(4)));
typedef _Float16 f16x8   __attribute__((ext_vector_type(8)));
typedef float    f32x4   __attribute__((ext_vector_type(4)));

// async global->LDS; LDS dest is wave-uniform base + lane*size (m104/m173)
__device__ inline void stage16(_Float16* ldst, const _Float16* gsrc) {
#if __has_builtin(__builtin_amdgcn_global_load_lds)
    __builtin_amdgcn_global_load_lds(
        (const __attribute__((address_space(1))) unsigned int*)gsrc,
        (__attribute__((address_space(3))) unsigned int*)ldst, 16, 0, 0);
#else
    *(f16x8*)ldst = *(const f16x8*)gsrc;
#endif
}
__device__ inline void stage4(float* ldst, const float* gsrc) {
#if __has_builtin(__builtin_amdgcn_global_load_lds)
    __builtin_amdgcn_global_load_lds(
        (const __attribute__((address_space(1))) unsigned int*)gsrc,
        (__attribute__((address_space(3))) unsigned int*)ldst, 4, 0, 0);
#else
    ldst[threadIdx.x & 63] = gsrc[0];
#endif
}

// ---------------------------------------------------------------------------
// K1: Vsum[l,e] = sum_j emb[V_idx[l,j], e]; norms; hi/lo split copy
__global__ void vsum_kernel(const int* __restrict__ V_idx, const float* __restrict__ emb,
                            float* __restrict__ Vsum, _Float16* __restrict__ vsh,
                            _Float16* __restrict__ vsl, float* __restrict__ vnorm)
{
    int l = blockIdx.x, e = threadIdx.x;
    float s = 0.f;
#pragma unroll
    for (int j = 0; j < VLz; ++j) {
        int idx = V_idx[l * VLz + j];
        s += emb[(long)idx * Ez + e];
    }
    Vsum[l * Ez + e] = s;
    float t = s * SCL;
    _Float16 h = (_Float16)t;
    vsh[l * Ez + e] = h;
    vsl[l * Ez + e] = (_Float16)(t - (float)h);
    __shared__ float red[256];
    red[e] = s * s; __syncthreads();
    for (int off = 128; off > 0; off >>= 1) { if (e < off) red[e] += red[e + off]; __syncthreads(); }
    if (e == 0) vnorm[l] = sqrtf(red[0]);
}

// K2: xe gather, hi/lo
__global__ void xe_kernel(const int* __restrict__ x, const float* __restrict__ emb,
                          _Float16* __restrict__ xeh, _Float16* __restrict__ xel)
{
    int i = blockIdx.x;              // b*S+s
    int e = threadIdx.x;
    float v = emb[(long)x[i] * Ez + e] * SCL;
    _Float16 h = (_Float16)v;
    xeh[(long)i * Ez + e] = h;
    xel[(long)i * Ez + e] = (_Float16)(v - (float)h);
}

// K3: pack w_hh into MFMA B-fragment order for the GRU.
// wqm[((dir*8+w)*48 + f*8+kk)*64 + lane] = f16x8 of
//   W_dir[o][kb..kb+7], o = (f>>1)*256 + 32w + 16(f&1) + (lane&15),
//   kb = kk*32 + (lane>>4)*8.   (f = gate*2 + p)
__global__ void wpackm_kernel(const float* __restrict__ w_f, const float* __restrict__ w_b,
                              f16x8* __restrict__ wqm)
{
    int id = blockIdx.x * 256 + threadIdx.x;     // 0 .. 49151
    int lane = id & 63;
    int rest = id >> 6;
    int kk = rest & 7;
    int f  = (rest >> 3) % 6;
    int dw = rest / 48;
    int dir = dw >> 3, w = dw & 7;
    const float* W = dir ? w_b : w_f;
    int o  = (f >> 1) * 256 + 32 * w + 16 * (f & 1) + (lane & 15);
    int kb = kk * 32 + (lane >> 4) * 8;
    f16x8 v;
#pragma unroll
    for (int j = 0; j < 8; ++j) v[j] = (_Float16)W[o * 256 + kb + j];
    wqm[id] = v;
}

// f32 -> scaled hi/lo f16
__global__ void cvtsplit_kernel(const float* __restrict__ in, _Float16* __restrict__ hi,
                                _Float16* __restrict__ lo, int n)
{
    int i = blockIdx.x * 256 + threadIdx.x;
    if (i < n) {
        float v = in[i] * SCL;
        _Float16 h = (_Float16)v;
        hi[i] = h;
        lo[i] = (_Float16)(v - (float)h);
    }
}

// ---------------------------------------------------------------------------
// Split-precision MFMA NT GEMM (round-4 proven): C = (1/4096)*(Ah+Al)@(Bh+Bl)^T.
template<int EPI, int BIAS, int OUTM, int SPLIT_A>
__global__ __launch_bounds__(256, 2) void gemm_mfma(
    const _Float16* __restrict__ Ah, const _Float16* __restrict__ Al,
    const _Float16* __restrict__ Bh, const _Float16* __restrict__ Bl,
    const float* __restrict__ bias, float* __restrict__ C,
    _Float16* __restrict__ Ch, _Float16* __restrict__ Cl,
    int M, int N, int K, long sA, long sB, long sC)
{
    int bz = blockIdx.z;
    Ah += (long)bz * sA;
    if (SPLIT_A) Al += (long)bz * sA;
    Bh += (long)bz * sB;
    Bl += (long)bz * sB;
    __shared__ __attribute__((aligned(16))) _Float16 Ash[128 * 32];
    __shared__ __attribute__((aligned(16))) _Float16 Asl[128 * 32];
    __shared__ __attribute__((aligned(16))) _Float16 Bsh[128 * 32];
    __shared__ __attribute__((aligned(16))) _Float16 Bsl[128 * 32];
    int tid = threadIdx.x;
    int lane = tid & 63;
    int wid = tid >> 6;
    int wm = wid >> 1, wn = wid & 1;
    int m0 = blockIdx.y * 128, n0 = blockIdx.x * 128;

    int srow = tid >> 2, sslot = tid & 3;
    int sw0 = sslot ^ ((srow >> 1) & 3);
    long a0 = (long)(m0 + srow) * K + sw0 * 8;
    long a1 = (long)(m0 + 64 + srow) * K + sw0 * 8;
    long b0 = (long)(n0 + srow) * K + sw0 * 8;
    long b1 = (long)(n0 + 64 + srow) * K + sw0 * 8;

    f32x4 acc[4][4] = {};
    int r16 = lane & 15, kg = lane >> 4;

    for (int k0 = 0; k0 < K; k0 += 32) {
        stage16(&Ash[tid * 8],        Ah + a0 + k0);
        stage16(&Ash[2048 + tid * 8], Ah + a1 + k0);
        if (SPLIT_A) {
            stage16(&Asl[tid * 8],        Al + a0 + k0);
            stage16(&Asl[2048 + tid * 8], Al + a1 + k0);
        }
        stage16(&Bsh[tid * 8],        Bh + b0 + k0);
        stage16(&Bsh[2048 + tid * 8], Bh + b1 + k0);
        stage16(&Bsl[tid * 8],        Bl + b0 + k0);
        stage16(&Bsl[2048 + tid * 8], Bl + b1 + k0);
        __syncthreads();
        f16x8 afh[4], afl[4], bfh[4], bfl[4];
#pragma unroll
        for (int mi = 0; mi < 4; ++mi) {
            int r = wm * 64 + mi * 16 + r16;
            int sl = kg ^ ((r >> 1) & 3);
            int off = r * 32 + sl * 8;
            afh[mi] = *(const f16x8*)&Ash[off];
            if (SPLIT_A) afl[mi] = *(const f16x8*)&Asl[off];
        }
#pragma unroll
        for (int ni = 0; ni < 4; ++ni) {
            int n = wn * 64 + ni * 16 + r16;
            int sl = kg ^ ((n >> 1) & 3);
            int off = n * 32 + sl * 8;
            bfh[ni] = *(const f16x8*)&Bsh[off];
            bfl[ni] = *(const f16x8*)&Bsl[off];
        }
#pragma unroll
        for (int mi = 0; mi < 4; ++mi)
#pragma unroll
            for (int ni = 0; ni < 4; ++ni) {
                acc[mi][ni] = __builtin_amdgcn_mfma_f32_16x16x32_f16(afh[mi], bfh[ni], acc[mi][ni], 0, 0, 0);
                acc[mi][ni] = __builtin_amdgcn_mfma_f32_16x16x32_f16(afh[mi], bfl[ni], acc[mi][ni], 0, 0, 0);
                if (SPLIT_A)
                    acc[mi][ni] = __builtin_amdgcn_mfma_f32_16x16x32_f16(afl[mi], bfh[ni], acc[mi][ni], 0, 0, 0);
            }
        __syncthreads();
    }

    long coff = (long)bz * sC;
#pragma unroll
    for (int mi = 0; mi < 4; ++mi) {
#pragma unroll
        for (int ni = 0; ni < 4; ++ni) {
            int n = n0 + wn * 64 + ni * 16 + r16;
            float bv = BIAS ? bias[n] : 0.f;
#pragma unroll
            for (int j = 0; j < 4; ++j) {
                int m = m0 + wm * 64 + mi * 16 + kg * 4 + j;
                float v = acc[mi][ni][j] * DESCL + bv;
                if (EPI == 1) v = fmaxf(v, 0.f);
                if (EPI == 2) v = tanhf(v);
                long idx = coff + (long)m * N + n;
                if (OUTM == 0) {
                    C[idx] = v;
                } else if (OUTM == 1) {
                    float t = v * SCL;
                    _Float16 h = (_Float16)t;
                    Ch[idx] = h;
                    Cl[idx] = (_Float16)(t - (float)h);
                } else {
                    Ch[idx] = (_Float16)(v * SCL);
                }
            }
        }
    }
}

// ---------------------------------------------------------------------------
// K4: GRU recurrence via MFMA. Grid = 16 blocks (dir = blk>>3, 8 batches each),
// 512 threads = 8 waves at 2/SIMD (cap 256 VGPR). Wave w owns outputs
// t in [32w,32w+32): 6 B-frag n-tiles (f = gate*2+p) x 8 k-tiles = 48 frags =
// 192 VGPR, register-pinned. Per step: 16 ds_read_b128 A-frags + 48 MFMAs
// (2 p-passes, acc 12 VGPR), lane-local gate math, gx prefetched one step
// ahead via global_load_lds into per-wave LDS slots (counted vmcnt), d hi/lo
// staged in LDS, dumped coalesced next step. ONE barrier/step (buffer-parity:
// buffer X is read only in steps where cur==X, written only the step before).
__global__ __launch_bounds__(512, 2) void gru_kernel(
    const float* __restrict__ gx_f, const float* __restrict__ gx_b,
    const f16x8* __restrict__ wqm,
    const float* __restrict__ bhh_f, const float* __restrict__ bhh_b,
    _Float16* __restrict__ dh_out, _Float16* __restrict__ dl_out)
{
    const int dir = blockIdx.x >> 3;
    const int b0  = (blockIdx.x & 7) * 8;
    const float* gx  = dir ? gx_b : gx_f;
    const float* bhh = dir ? bhh_b : bhh_f;
    const int tid = threadIdx.x;
    const int w   = tid >> 6;
    const int l   = tid & 63;
    const int np  = l & 15;
    const int lg  = l >> 4;

    __shared__ __attribute__((aligned(16))) _Float16 hbuf[2][16][264];
    __shared__ __attribute__((aligned(16))) float    gxbuf[2][8][12][64];
    __shared__ __attribute__((aligned(16))) _Float16 dsth[2][8][256];
    __shared__ __attribute__((aligned(16))) _Float16 dstl[2][8][256];

    // weights -> registers (48 f16x8), pinned
    f16x8 wf[48];
    const f16x8* wb = wqm + (size_t)(dir * 8 + w) * 48 * 64 + l;
#pragma unroll
    for (int i = 0; i < 48; ++i) wf[i] = wb[i * 64];
#pragma unroll
    for (int i = 0; i < 48; ++i) asm volatile("" : "+v"(wf[i]));

    // per-lane biases [gate][p]
    float bias[6];
#pragma unroll
    for (int g = 0; g < 3; ++g)
#pragma unroll
        for (int p = 0; p < 2; ++p)
            bias[g * 2 + p] = bhh[g * 256 + 32 * w + 16 * p + np];

    // zero h (both buffers, all 16 rows; rows 8..15 stay zero = m-padding)
    for (int i = tid; i < 2 * 16 * 264; i += 512) ((_Float16*)hbuf)[i] = (_Float16)0.f;

    // prologue: prefetch gx for step 0 into gxbuf[0]
    {
        int ss = dir ? (Sz - 1) : 0;
        int mgl = (l >> 5);          // 0/1
        int tl  = l & 31;
#pragma unroll
        for (int g = 0; g < 3; ++g)
#pragma unroll
            for (int jj = 0; jj < 4; ++jj) {
                int m = 2 * jj + mgl;
                stage4(&gxbuf[0][w][g * 4 + jj][0],
                       gx + ((size_t)(b0 + m) * Sz + ss) * 768 + g * 256 + 32 * w + tl);
            }
    }
    __syncthreads();

    for (int step = 0; step < Sz; ++step) {
        const int cur = step & 1, nxt = cur ^ 1;
        // ---- dump previous step's d staging (coalesced, 2 stores) ----
        if (step > 0) {
            int sp = dir ? (Sz - step) : (step - 1);
            int m = tid >> 6;
            int off = (tid & 63) * 4;
            size_t gi = ((size_t)(b0 + m) * Sz + sp) * 512 + dir * 256 + off;
            *(f16x4*)&dh_out[gi] = *(const f16x4*)&dsth[nxt][m][off];
            *(f16x4*)&dl_out[gi] = *(const f16x4*)&dstl[nxt][m][off];
        }
        // ---- prefetch gx for step+1 (clamped at the end; 12 loads) ----
        {
            int sn;
            if (step + 1 < Sz) sn = dir ? (Sz - 2 - step) : (step + 1);
            else               sn = dir ? 0 : (Sz - 1);
            int mgl = (l >> 5);
            int tl  = l & 31;
#pragma unroll
            for (int g = 0; g < 3; ++g)
#pragma unroll
                for (int jj = 0; jj < 4; ++jj) {
                    int m = 2 * jj + mgl;
                    stage4(&gxbuf[nxt][w][g * 4 + jj][0],
                           gx + ((size_t)(b0 + m) * Sz + sn) * 768 + g * 256 + 32 * w + tl);
                }
        }
        // ---- two p-passes: 24 MFMA each, then lane-local gates ----
#pragma unroll
        for (int p = 0; p < 2; ++p) {
            f32x4 a0 = {}, a1 = {}, a2 = {};
#pragma unroll
            for (int kk = 0; kk < 8; ++kk) {
                f16x8 af = *(const f16x8*)&hbuf[cur][np][kk * 32 + lg * 8];
                a0 = __builtin_amdgcn_mfma_f32_16x16x32_f16(af, wf[(0 + p) * 8 + kk], a0, 0, 0, 0);
                a1 = __builtin_amdgcn_mfma_f32_16x16x32_f16(af, wf[(2 + p) * 8 + kk], a1, 0, 0, 0);
                a2 = __builtin_amdgcn_mfma_f32_16x16x32_f16(af, wf[(4 + p) * 8 + kk], a2, 0, 0, 0);
            }
            if (p == 0) {
                // drain everything older than this step's 12 prefetch loads
                // (+2 dump stores when step>0) so gxbuf[cur] is valid.
                if (step == 0) asm volatile("s_waitcnt vmcnt(12)" ::: "memory");
                else           asm volatile("s_waitcnt vmcnt(14)" ::: "memory");
                __builtin_amdgcn_sched_barrier(0);
            }
            if (lg < 2) {
                int t = 32 * w + 16 * p + np;
#pragma unroll
                for (int j = 0; j < 4; ++j) {
                    int m = 4 * lg + j;
                    int pos = (m & 1) * 32 + 16 * p + np;
                    float xr = gxbuf[cur][w][0 + (m >> 1)][pos];
                    float xz = gxbuf[cur][w][4 + (m >> 1)][pos];
                    float xn = gxbuf[cur][w][8 + (m >> 1)][pos];
                    float r  = 1.f / (1.f + __expf(-(xr + bias[0 * 2 + p] + a0[j])));
                    float z  = 1.f / (1.f + __expf(-(xz + bias[1 * 2 + p] + a1[j])));
                    float nn = tanhf(xn + r * (a2[j] + bias[2 * 2 + p]));
                    float ho = (float)hbuf[cur][m][t];
                    float hn = (1.f - z) * nn + z * ho;
                    hbuf[nxt][m][t] = (_Float16)hn;
                    float hs = hn * SCL;
                    _Float16 hh = (_Float16)hs;
                    dsth[cur][m][t] = hh;
                    dstl[cur][m][t] = (_Float16)(hs - (float)hh);
                }
            }
        }
        __syncthreads();
    }
    // epilogue: dump the final step's d staging
    {
        int sp = dir ? 0 : (Sz - 1);
        int m = tid >> 6;
        int off = (tid & 63) * 4;
        size_t gi = ((size_t)(b0 + m) * Sz + sp) * 512 + dir * 256 + off;
        *(f16x4*)&dh_out[gi] = *(const f16x4*)&dsth[(Sz - 1) & 1][m][off];
        *(f16x4*)&dl_out[gi] = *(const f16x4*)&dstl[(Sz - 1) & 1][m][off];
    }
}

// ---------------------------------------------------------------------------
// transpose d (hi,lo) [B*S][512] -> dT (hi,lo) [B][512][256]
__global__ __launch_bounds__(256) void dtrans_kernel(
    const _Float16* __restrict__ dh, const _Float16* __restrict__ dl,
    _Float16* __restrict__ dTh, _Float16* __restrict__ dTl)
{
    __shared__ _Float16 th[64][68];
    __shared__ _Float16 tl[64][68];
    int s0 = blockIdx.x << 6;
    int h0 = blockIdx.y << 6;
    int b  = blockIdx.z;
    int tid = threadIdx.x;
#pragma unroll
    for (int i = 0; i < 16; ++i) {
        int idx = tid + i * 256;
        int s = idx >> 6, h = idx & 63;
        size_t gi = (size_t)(b * 256 + s0 + s) * 512 + h0 + h;
        th[s][h] = dh[gi];
        tl[s][h] = dl[gi];
    }
    __syncthreads();
#pragma unroll
    for (int i = 0; i < 16; ++i) {
        int idx = tid + i * 256;
        int h = idx >> 6, s = idx & 63;
        size_t gi = (size_t)(b * 512 + h0 + h) * 256 + s0 + s;
        dTh[gi] = th[s][h];
        dTl[gi] = tl[s][h];
    }
}

// ---------------------------------------------------------------------------
// BN stats over (b, e) for each channel c (layout y[b][CH][256])
__global__ void bn_stats_kernel(const float* __restrict__ y, int CH,
                                float* __restrict__ mean, float* __restrict__ istd)
{
    int c = blockIdx.x, t = threadIdx.x;
    float s = 0.f, ss = 0.f;
    for (int b = 0; b < Bz; ++b) {
        float v = y[((long)b * CH + c) * 256 + t];
        s += v; ss += v * v;
    }
    __shared__ float rs[256], rss[256];
    rs[t] = s; rss[t] = ss; __syncthreads();
    for (int off = 128; off > 0; off >>= 1) {
        if (t < off) { rs[t] += rs[t + off]; rss[t] += rss[t + off]; }
        __syncthreads();
    }
    if (t == 0) {
        float cnt = (float)(Bz * 256);
        float m = rs[0] / cnt;
        float var = rss[0] / cnt - m * m;
        mean[c] = m;
        istd[c] = rsqrtf(var + 1e-5f);
    }
}

// BN apply + activation. HL=1: write scaled hi/lo f16; HL=0: in-place f32.
template<int EPI, int HL>
__global__ void bn_apply_kernel(float* __restrict__ y, _Float16* __restrict__ yh,
                                _Float16* __restrict__ yl, int CH,
                                const float* __restrict__ mean, const float* __restrict__ istd,
                                const float* __restrict__ g, const float* __restrict__ be)
{
    long i = (long)blockIdx.x * 256 + threadIdx.x;
    int c = (int)((i >> 8) % CH);
    float v = (y[i] - mean[c]) * istd[c] * g[c] + be[c];
    v = (EPI == 1) ? fmaxf(v, 0.f) : tanhf(v);
    if (HL) {
        float t = v * SCL;
        _Float16 h = (_Float16)t;
        yh[i] = h;
        yl[i] = (_Float16)(t - (float)h);
    } else {
        y[i] = v;
    }
}

// ---------------------------------------------------------------------------
// Output: cosine similarity * 10
__global__ void out_kernel(const float* __restrict__ e, const float* __restrict__ Vsum,
                           const float* __restrict__ vnorm, float* __restrict__ out)
{
    int bl = blockIdx.x;
    int l = bl & (Lz - 1);
    int t = threadIdx.x;
    float ev = e[(long)bl * 256 + t];
    float vv = Vsum[l * 256 + t];
    __shared__ float rd[256], rn[256];
    rd[t] = ev * vv; rn[t] = ev * ev; __syncthreads();
    for (int off = 128; off > 0; off >>= 1) {
        if (t < off) { rd[t] += rd[t + off]; rn[t] += rn[t + off]; }
        __syncthreads();
    }
    if (t == 0) {
        float num = rd[0];
        float den = fmaxf(sqrtf(rn[0]), 1e-8f) * fmaxf(vnorm[l], 1e-8f);
        out[bl] = num / den * 10.f;
    }
}

// ---------------------------------------------------------------------------
extern "C" void kernel_launch(void* const* d_in, const int* in_sizes, int n_in,
                              void* d_out, int out_size, void* d_ws, size_t ws_size,
                              hipStream_t stream)
{
    const int*   x      = (const int*)d_in[0];
    const int*   V_idx  = (const int*)d_in[1];
    const float* emb    = (const float*)d_in[2];
    const float* w_ih_f = (const float*)d_in[3];
    const float* w_hh_f = (const float*)d_in[4];
    const float* b_ih_f = (const float*)d_in[5];
    const float* b_hh_f = (const float*)d_in[6];
    const float* w_ih_b = (const float*)d_in[7];
    const float* w_hh_b = (const float*)d_in[8];
    const float* b_ih_b = (const float*)d_in[9];
    const float* b_hh_b = (const float*)d_in[10];
    const float* w1     = (const float*)d_in[11];
    const float* b1     = (const float*)d_in[12];
    const float* w2     = (const float*)d_in[13];
    const float* b2     = (const float*)d_in[14];
    const float* g1     = (const float*)d_in[15];
    const float* be1    = (const float*)d_in[16];
    const float* g2     = (const float*)d_in[17];
    const float* be2    = (const float*)d_in[18];

    float* ws = (float*)d_ws;
    float* out = (float*)d_out;

    // ---- workspace layout (float units); total ~207 MB ----
    float*    vsum   = ws;                               // 262144
    float*    vnorm  = ws + 262144;                      // 1024
    float*    mean   = ws + 263168;                      // 1024
    float*    istd   = ws + 264192;                      // 1024
    f16x8*    wqm    = (f16x8*)(ws + 265216);            // 196608 fl (MFMA pack)
    _Float16* vsh    = (_Float16*)(ws + 461824);         // 131072 fl
    _Float16* vsl    = (_Float16*)(ws + 592896);         // 131072 fl
    _Float16* wihh_f = (_Float16*)(ws + 723968);         // 98304 fl
    _Float16* wihl_f = (_Float16*)(ws + 822272);         // 98304 fl
    _Float16* wihh_b = (_Float16*)(ws + 920576);         // 98304 fl
    _Float16* wihl_b = (_Float16*)(ws + 1018880);        // 98304 fl
    _Float16* w1h    = (_Float16*)(ws + 1117184);        // 65536 fl
    _Float16* w1l    = (_Float16*)(ws + 1182720);        // 65536 fl
    _Float16* w2h    = (_Float16*)(ws + 1248256);        // 65536 fl
    _Float16* w2l    = (_Float16*)(ws + 1313792);        // 65536 fl
    float*    AB     = ws + 1379328;                     // overlay arena
    _Float16* xeh    = (_Float16*)(AB + 0);              // st1-2
    _Float16* xel    = (_Float16*)(AB + 2097152);
    float*    gxf    = AB + 4194304;                     // st2-3
    float*    gxb    = AB + 16777216;
    _Float16* dh     = (_Float16*)(AB + 29360128);       // st3-4 (+dtrans)
    _Float16* dl     = (_Float16*)(AB + 33554432);
    _Float16* dTh    = (_Float16*)(AB + 0);              // dtrans-st6 (xe/gx dead)
    _Float16* dTl    = (_Float16*)(AB + 4194304);
    float*    d2pre  = AB + 8388608;                     // st4 (gx dead)
    _Float16* d2h    = (_Float16*)(AB + 12582912);       // st4-5
    _Float16* d2l    = (_Float16*)(AB + 14680064);
    _Float16* ah     = (_Float16*)(AB + 16777216);       // st5-6 (gxb/d dead)
    _Float16* al     = (_Float16*)(AB + 25165824);
    _Float16* c16    = (_Float16*)(AB + 33554432);       // st6-7 (dl dead)
    float*    epre   = AB + 0;                           // st7-8 (dT/d2 dead)

    // Stage 1: gathers + packs
    vsum_kernel<<<Lz, 256, 0, stream>>>(V_idx, emb, vsum, vsh, vsl, vnorm);
    xe_kernel<<<Bz * Sz, 256, 0, stream>>>(x, emb, xeh, xel);
    wpackm_kernel<<<192, 256, 0, stream>>>(w_hh_f, w_hh_b, wqm);
    cvtsplit_kernel<<<768, 256, 0, stream>>>(w_ih_f, wihh_f, wihl_f, 196608);
    cvtsplit_kernel<<<768, 256, 0, stream>>>(w_ih_b, wihh_b, wihl_b, 196608);
    cvtsplit_kernel<<<512, 256, 0, stream>>>(w1, w1h, w1l, 131072);
    cvtsplit_kernel<<<512, 256, 0, stream>>>(w2, w2h, w2l, 131072);

    // Stage 2: gx = xe @ w_ih^T + b_ih  (M=16384, N=768, K=256), f32 out
    gemm_mfma<0, 1, 0, 1><<<dim3(6, 128, 1), 256, 0, stream>>>(
        xeh, xel, wihh_f, wihl_f, b_ih_f, gxf, nullptr, nullptr, Bz * Sz, 768, Ez, 0, 0, 0);
    gemm_mfma<0, 1, 0, 1><<<dim3(6, 128, 1), 256, 0, stream>>>(
        xeh, xel, wihh_b, wihl_b, b_ih_b, gxb, nullptr, nullptr, Bz * Sz, 768, Ez, 0, 0, 0);

    // Stage 3: GRU (MFMA) -> d hi/lo [B,S,512]; transpose -> dT [B,512,256]
    gru_kernel<<<16, 512, 0, stream>>>(gxf, gxb, wqm, b_hh_f, b_hh_b, dh, dl);
    dtrans_kernel<<<dim3(4, 8, Bz), 256, 0, stream>>>(dh, dl, dTh, dTl);

    // Stage 4: d2pre = d @ w1^T + b1 (M=16384, N=256, K=512) f32; BN1+relu -> hi/lo
    gemm_mfma<0, 1, 0, 1><<<dim3(2, 128, 1), 256, 0, stream>>>(
        dh, dl, w1h, w1l, b1, d2pre, nullptr, nullptr, Bz * Sz, Ez, 512, 0, 0, 0);
    bn_stats_kernel<<<Sz, 256, 0, stream>>>(d2pre, Sz, mean, istd);
    bn_apply_kernel<1, 1><<<Bz * Sz, 256, 0, stream>>>(d2pre, d2h, d2l, Sz, mean, istd, g1, be1);

    // Stage 5: a[b] = tanh(Vsum @ d2[b]^T)  (M=1024, N=256, K=256) -> hi/lo
    gemm_mfma<2, 0, 1, 1><<<dim3(2, 8, Bz), 256, 0, stream>>>(
        vsh, vsl, d2h, d2l, nullptr, nullptr, ah, al, Lz, Sz, Ez, 0, (long)Sz * Ez, (long)Lz * Sz);

    // Stage 6: c[b] = relu(a[b] @ dT[b]^T)  (M=1024, N=512, K=256) -> hi only
    gemm_mfma<1, 0, 2, 1><<<dim3(4, 8, Bz), 256, 0, stream>>>(
        ah, al, dTh, dTl, nullptr, nullptr, c16, nullptr, Lz, 512, Sz,
        (long)Lz * Sz, (long)512 * Sz, (long)Lz * 512);

    // Stage 7: epre = c @ w2^T + b2 (M=65536, N=256, K=512, A hi-only) f32; BN2+tanh
    gemm_mfma<0, 1, 0, 0><<<dim3(2, 512, 1), 256, 0, stream>>>(
        c16, nullptr, w2h, w2l, b2, epre, nullptr, nullptr, Bz * Lz, Ez, 512, 0, 0, 0);
    bn_stats_kernel<<<Lz, 256, 0, stream>>>(epre, Lz, mean, istd);
    bn_apply_kernel<2, 0><<<Bz * Lz, 256, 0, stream>>>(epre, nullptr, nullptr, Lz, mean, istd, g2, be2);

    // Stage 8: output
    out_kernel<<<Bz * Lz, 256, 0, stream>>>(epre, vsum, vnorm, out);
}

// Round 9
// 776.692 us; speedup vs baseline: 1.5051x; 1.4334x over previous
//
#include <hip/hip_runtime.h>
#include <hip/hip_bf16.h>

// Sizes (fixed per problem)
#define Bz 64
#define Sz 256
#define Ez 256
#define Hz 256
#define Lz 1024
#define VLz 16

// split-precision scale: x stored as hi+lo of (x*SCL); products carry SCL^2
#define SCL 64.0f
#define DESCL (1.0f / 4096.0f)

// GRU hybrid: k-quads per k-half held in LDS (JL) vs streamed from L2 (JS)
#define JL 12
#define JS (32 - JL)

typedef _Float16 half2_t __attribute__((ext_vector_type(2)));
typedef _Float16 half4_t __attribute__((ext_vector_type(4)));
typedef _Float16 f16x8   __attribute__((ext_vector_type(8)));
typedef float    f32x4   __attribute__((ext_vector_type(4)));

__device__ inline float fdot2(half2_t a, half2_t b, float c) {
#if __has_builtin(__builtin_amdgcn_fdot2)
    return __builtin_amdgcn_fdot2(a, b, c, false);
#else
    return c + (float)a[0] * (float)b[0] + (float)a[1] * (float)b[1];
#endif
}

// async global->LDS 16B; LDS dest must be linear lane-ordered (m104/m173)
__device__ inline void stage16(_Float16* ldst, const _Float16* gsrc) {
#if __has_builtin(__builtin_amdgcn_global_load_lds)
    __builtin_amdgcn_global_load_lds(
        (const __attribute__((address_space(1))) unsigned int*)gsrc,
        (__attribute__((address_space(3))) unsigned int*)ldst, 16, 0, 0);
#else
    *(f16x8*)ldst = *(const f16x8*)gsrc;
#endif
}

// ---------------------------------------------------------------------------
// K1: Vsum[l,e] = sum_j emb[V_idx[l,j], e]; norms; hi/lo split copy
__global__ void vsum_kernel(const int* __restrict__ V_idx, const float* __restrict__ emb,
                            float* __restrict__ Vsum, _Float16* __restrict__ vsh,
                            _Float16* __restrict__ vsl, float* __restrict__ vnorm)
{
    int l = blockIdx.x, e = threadIdx.x;
    float s = 0.f;
#pragma unroll
    for (int j = 0; j < VLz; ++j) {
        int idx = V_idx[l * VLz + j];
        s += emb[(long)idx * Ez + e];
    }
    Vsum[l * Ez + e] = s;
    float t = s * SCL;
    _Float16 h = (_Float16)t;
    vsh[l * Ez + e] = h;
    vsl[l * Ez + e] = (_Float16)(t - (float)h);
    __shared__ float red[256];
    red[e] = s * s; __syncthreads();
    for (int off = 128; off > 0; off >>= 1) { if (e < off) red[e] += red[e + off]; __syncthreads(); }
    if (e == 0) vnorm[l] = sqrtf(red[0]);
}

// K2: xe gather, hi/lo
__global__ void xe_kernel(const int* __restrict__ x, const float* __restrict__ emb,
                          _Float16* __restrict__ xeh, _Float16* __restrict__ xel)
{
    int i = blockIdx.x;              // b*S+s
    int e = threadIdx.x;
    float v = emb[(long)x[i] * Ez + e] * SCL;
    _Float16 h = (_Float16)v;
    xeh[(long)i * Ez + e] = h;
    xel[(long)i * Ez + e] = (_Float16)(v - (float)h);
}

// K3: pack w_hh [768,256] fp32 -> f16x2 quad layout for the GRU (round-2/4 proven).
// out index i = ((kq*3+g)*2+p)*256 + t  holds (w[g*256+t][4kq+2p], w[g*256+t][4kq+2p+1])
__global__ void wpack_kernel(const float* __restrict__ w_f, const float* __restrict__ w_b,
                             half2_t* __restrict__ out_f, half2_t* __restrict__ out_b)
{
    int i = blockIdx.x * 256 + threadIdx.x;   // 0 .. 98303
    int t = i & 255;
    int rest = i >> 8;          // (kq*3+g)*2+p
    int p = rest & 1;
    int gq = rest >> 1;
    int g = gq % 3;
    int kq = gq / 3;
    int o = g * 256 + t;
    int k = 4 * kq + 2 * p;
    out_f[i] = half2_t{(_Float16)w_f[o * 256 + k], (_Float16)w_f[o * 256 + k + 1]};
    out_b[i] = half2_t{(_Float16)w_b[o * 256 + k], (_Float16)w_b[o * 256 + k + 1]};
}

// f32 -> scaled hi/lo f16
__global__ void cvtsplit_kernel(const float* __restrict__ in, _Float16* __restrict__ hi,
                                _Float16* __restrict__ lo, int n)
{
    int i = blockIdx.x * 256 + threadIdx.x;
    if (i < n) {
        float v = in[i] * SCL;
        _Float16 h = (_Float16)v;
        hi[i] = h;
        lo[i] = (_Float16)(v - (float)h);
    }
}

// ---------------------------------------------------------------------------
// Split-precision MFMA NT GEMM (round-4 proven): C = (1/4096)*(Ah+Al)@(Bh+Bl)^T.
// acc = Ah*Bh + Ah*Bl (+ Al*Bh if SPLIT_A). BM=BN=128, BK=32, 4 waves 2x2.
// OUTM: 0 = f32 C, 1 = scaled hi/lo f16 (Ch,Cl), 2 = scaled hi f16 only.
template<int EPI, int BIAS, int OUTM, int SPLIT_A>
__global__ __launch_bounds__(256, 2) void gemm_mfma(
    const _Float16* __restrict__ Ah, const _Float16* __restrict__ Al,
    const _Float16* __restrict__ Bh, const _Float16* __restrict__ Bl,
    const float* __restrict__ bias, float* __restrict__ C,
    _Float16* __restrict__ Ch, _Float16* __restrict__ Cl,
    int M, int N, int K, long sA, long sB, long sC)
{
    int bz = blockIdx.z;
    Ah += (long)bz * sA;
    if (SPLIT_A) Al += (long)bz * sA;
    Bh += (long)bz * sB;
    Bl += (long)bz * sB;
    __shared__ __attribute__((aligned(16))) _Float16 Ash[128 * 32];
    __shared__ __attribute__((aligned(16))) _Float16 Asl[128 * 32];
    __shared__ __attribute__((aligned(16))) _Float16 Bsh[128 * 32];
    __shared__ __attribute__((aligned(16))) _Float16 Bsl[128 * 32];
    int tid = threadIdx.x;
    int lane = tid & 63;
    int wid = tid >> 6;
    int wm = wid >> 1, wn = wid & 1;
    int m0 = blockIdx.y * 128, n0 = blockIdx.x * 128;

    int srow = tid >> 2, sslot = tid & 3;
    int sw0 = sslot ^ ((srow >> 1) & 3);
    long a0 = (long)(m0 + srow) * K + sw0 * 8;
    long a1 = (long)(m0 + 64 + srow) * K + sw0 * 8;
    long b0 = (long)(n0 + srow) * K + sw0 * 8;
    long b1 = (long)(n0 + 64 + srow) * K + sw0 * 8;

    f32x4 acc[4][4] = {};
    int r16 = lane & 15, kg = lane >> 4;

    for (int k0 = 0; k0 < K; k0 += 32) {
        stage16(&Ash[tid * 8],        Ah + a0 + k0);
        stage16(&Ash[2048 + tid * 8], Ah + a1 + k0);
        if (SPLIT_A) {
            stage16(&Asl[tid * 8],        Al + a0 + k0);
            stage16(&Asl[2048 + tid * 8], Al + a1 + k0);
        }
        stage16(&Bsh[tid * 8],        Bh + b0 + k0);
        stage16(&Bsh[2048 + tid * 8], Bh + b1 + k0);
        stage16(&Bsl[tid * 8],        Bl + b0 + k0);
        stage16(&Bsl[2048 + tid * 8], Bl + b1 + k0);
        __syncthreads();
        f16x8 afh[4], afl[4], bfh[4], bfl[4];
#pragma unroll
        for (int mi = 0; mi < 4; ++mi) {
            int r = wm * 64 + mi * 16 + r16;
            int sl = kg ^ ((r >> 1) & 3);
            int off = r * 32 + sl * 8;
            afh[mi] = *(const f16x8*)&Ash[off];
            if (SPLIT_A) afl[mi] = *(const f16x8*)&Asl[off];
        }
#pragma unroll
        for (int ni = 0; ni < 4; ++ni) {
            int n = wn * 64 + ni * 16 + r16;
            int sl = kg ^ ((n >> 1) & 3);
            int off = n * 32 + sl * 8;
            bfh[ni] = *(const f16x8*)&Bsh[off];
            bfl[ni] = *(const f16x8*)&Bsl[off];
        }
#pragma unroll
        for (int mi = 0; mi < 4; ++mi)
#pragma unroll
            for (int ni = 0; ni < 4; ++ni) {
                acc[mi][ni] = __builtin_amdgcn_mfma_f32_16x16x32_f16(afh[mi], bfh[ni], acc[mi][ni], 0, 0, 0);
                acc[mi][ni] = __builtin_amdgcn_mfma_f32_16x16x32_f16(afh[mi], bfl[ni], acc[mi][ni], 0, 0, 0);
                if (SPLIT_A)
                    acc[mi][ni] = __builtin_amdgcn_mfma_f32_16x16x32_f16(afl[mi], bfh[ni], acc[mi][ni], 0, 0, 0);
            }
        __syncthreads();
    }

    long coff = (long)bz * sC;
#pragma unroll
    for (int mi = 0; mi < 4; ++mi) {
#pragma unroll
        for (int ni = 0; ni < 4; ++ni) {
            int n = n0 + wn * 64 + ni * 16 + r16;
            float bv = BIAS ? bias[n] : 0.f;
#pragma unroll
            for (int j = 0; j < 4; ++j) {
                int m = m0 + wm * 64 + mi * 16 + kg * 4 + j;
                float v = acc[mi][ni][j] * DESCL + bv;
                if (EPI == 1) v = fmaxf(v, 0.f);
                if (EPI == 2) v = tanhf(v);
                long idx = coff + (long)m * N + n;
                if (OUTM == 0) {
                    C[idx] = v;
                } else if (OUTM == 1) {
                    float t = v * SCL;
                    _Float16 h = (_Float16)t;
                    Ch[idx] = h;
                    Cl[idx] = (_Float16)(t - (float)h);
                } else {
                    Ch[idx] = (_Float16)(v * SCL);
                }
            }
        }
    }
}

// ---------------------------------------------------------------------------
// K4: GRU recurrence, round-4 structure + hybrid weight residency.
// One block per (dir,batch), 512 threads = 8 waves. k-split 2: thread (q,t).
// Of the 32 k-quads per k-half, JL=12 live in LDS (147KB, filled once, read as
// minimum-aliasing ds_read_b128 in a [chunk][tid] 16B-cell layout) and JS=20
// are streamed from L2 each step (rounds 2/4/5/7: the allocator always
// re-streams weight arrays; streaming 120 instead of 192 dwords/thread cuts
// the L2-roofline time ~37%). Dynamic LDS 155,136 B -> 1 block/CU.
// Numerics identical to round 4 (same f16 weights, same fdot2 order class).
__global__ __launch_bounds__(512, 2) void gru_kernel(
    const float* __restrict__ gx_f, const float* __restrict__ gx_b,
    const half2_t* __restrict__ wq_f, const half2_t* __restrict__ wq_b,
    const float* __restrict__ bhh_f, const float* __restrict__ bhh_b,
    _Float16* __restrict__ dh_out, _Float16* __restrict__ dl_out)
{
    extern __shared__ __attribute__((aligned(16))) char smem[];
    half2_t*  wlds = (half2_t*)smem;                 // 2*JL*6*256 dw = 147456 B
    _Float16* hbuf = (_Float16*)(smem + 147456);     // 512 B
    float*    hf32 = (float*)(smem + 147968);        // 1024 B
    float*    part = (float*)(smem + 148992);        // 6144 B

    int dir = blockIdx.x >> 6;
    int b   = blockIdx.x & 63;
    const float*   gx  = dir ? gx_b : gx_f;
    const half2_t* wq  = dir ? wq_b : wq_f;
    const float*   bhh = dir ? bhh_b : bhh_f;
    int tid = threadIdx.x;
    int t = tid & 255, q = tid >> 8;

    // one-time LDS fill of the resident fraction (coalesced on t).
    for (int i = tid; i < 2 * JL * 6 * 256; i += 512) {
        int tt = i & 255;
        int rest = i >> 8;
        int d  = rest % (JL * 6);
        int qq = rest / (JL * 6);
        wlds[((size_t)(d >> 2) * 512 + qq * 256 + tt) * 4 + (d & 3)] =
            wq[((size_t)qq * 192 + d) * 256 + tt];
    }

    // streamed fraction: jj in [JL,32) -> wr[], re-streamed from L2 per step
    half2_t wr[JS * 6];
    const half2_t* wbase = wq + ((size_t)q * 192 + JL * 6) * 256 + t;
#pragma unroll
    for (int m = 0; m < JS * 6; ++m) wr[m] = wbase[m << 8];

    float br = 0.f, bz = 0.f, bn = 0.f, hprev = 0.f;
    if (q == 0) {
        br = bhh[t]; bz = bhh[256 + t]; bn = bhh[512 + t];
        hbuf[t] = (_Float16)0.f;
        hf32[t] = 0.f;
    }
    __syncthreads();

    const f16x8* wl16 = (const f16x8*)wlds;

    for (int step = 0; step < Sz; ++step) {
        int s = dir ? (Sz - 1 - step) : step;
        // deferred previous-step d write (overlaps dot phase)
        if (q == 1 && step > 0) {
            int sp = dir ? (Sz - step) : (step - 1);
            float hv = hf32[t] * SCL;
            _Float16 hh = (_Float16)hv;
            size_t idx = (size_t)(b * Sz + sp) * 512 + dir * 256 + t;
            dh_out[idx] = hh;
            dl_out[idx] = (_Float16)(hv - (float)hh);
        }
        const float* g = gx + (size_t)(b * Sz + s) * 768;
        float xr = 0.f, xz = 0.f, xn = 0.f;
        if (q == 0) { xr = g[t]; xz = g[256 + t]; xn = g[512 + t]; }

        float ar = 0.f, az = 0.f, an = 0.f;
        const half4_t* hp = (const half4_t*)hbuf;

        // LDS-resident quads, processed in jj-pairs (3 x b128 chunks each)
#pragma unroll
        for (int cj = 0; cj < JL / 2; ++cj) {
            f16x8 c0 = wl16[(3 * cj + 0) * 512 + tid];
            f16x8 c1 = wl16[(3 * cj + 1) * 512 + tid];
            f16x8 c2 = wl16[(3 * cj + 2) * 512 + tid];
            half4_t hv0 = hp[q * 32 + 2 * cj];
            half4_t hv1 = hp[q * 32 + 2 * cj + 1];
            half2_t a01 = {hv0[0], hv0[1]}, a23 = {hv0[2], hv0[3]};
            half2_t b01 = {hv1[0], hv1[1]}, b23 = {hv1[2], hv1[3]};
            ar = fdot2(half2_t{c0[0], c0[1]}, a01, ar);
            ar = fdot2(half2_t{c0[2], c0[3]}, a23, ar);
            az = fdot2(half2_t{c0[4], c0[5]}, a01, az);
            az = fdot2(half2_t{c0[6], c0[7]}, a23, az);
            an = fdot2(half2_t{c1[0], c1[1]}, a01, an);
            an = fdot2(half2_t{c1[2], c1[3]}, a23, an);
            ar = fdot2(half2_t{c1[4], c1[5]}, b01, ar);
            ar = fdot2(half2_t{c1[6], c1[7]}, b23, ar);
            az = fdot2(half2_t{c2[0], c2[1]}, b01, az);
            az = fdot2(half2_t{c2[2], c2[3]}, b23, az);
            an = fdot2(half2_t{c2[4], c2[5]}, b01, an);
            an = fdot2(half2_t{c2[6], c2[7]}, b23, an);
        }
        // streamed quads
#pragma unroll
        for (int jj = 0; jj < JS; ++jj) {
            half4_t hv = hp[q * 32 + JL + jj];
            half2_t h01 = {hv[0], hv[1]};
            half2_t h23 = {hv[2], hv[3]};
            ar = fdot2(wr[jj * 6 + 0], h01, ar); ar = fdot2(wr[jj * 6 + 1], h23, ar);
            az = fdot2(wr[jj * 6 + 2], h01, az); az = fdot2(wr[jj * 6 + 3], h23, az);
            an = fdot2(wr[jj * 6 + 4], h01, an); an = fdot2(wr[jj * 6 + 5], h23, an);
        }
        part[q * 768 + t]       = ar;
        part[q * 768 + 256 + t] = az;
        part[q * 768 + 512 + t] = an;
        __syncthreads();

        if (q == 0) {
            float hr = part[t]       + part[768 + t];
            float hz = part[256 + t] + part[768 + 256 + t];
            float hn = part[512 + t] + part[768 + 512 + t];
            float r  = 1.f / (1.f + expf(-(xr + br + hr)));
            float z  = 1.f / (1.f + expf(-(xz + bz + hz)));
            float nn = tanhf(xn + r * (hn + bn));
            hprev = (1.f - z) * nn + z * hprev;
            hbuf[t] = (_Float16)hprev;
            hf32[t] = hprev;
        }
        __syncthreads();
    }
    // final step's d write
    if (q == 1) {
        int sl = dir ? 0 : (Sz - 1);
        float hv = hf32[t] * SCL;
        _Float16 hh = (_Float16)hv;
        size_t idx = (size_t)(b * Sz + sl) * 512 + dir * 256 + t;
        dh_out[idx] = hh;
        dl_out[idx] = (_Float16)(hv - (float)hh);
    }
}

// ---------------------------------------------------------------------------
// transpose d (hi,lo) [B*S][512] -> dT (hi,lo) [B][512][256]
__global__ __launch_bounds__(256) void dtrans_kernel(
    const _Float16* __restrict__ dh, const _Float16* __restrict__ dl,
    _Float16* __restrict__ dTh, _Float16* __restrict__ dTl)
{
    __shared__ _Float16 th[64][68];
    __shared__ _Float16 tl[64][68];
    int s0 = blockIdx.x << 6;
    int h0 = blockIdx.y << 6;
    int b  = blockIdx.z;
    int tid = threadIdx.x;
#pragma unroll
    for (int i = 0; i < 16; ++i) {
        int idx = tid + i * 256;
        int s = idx >> 6, h = idx & 63;
        size_t gi = (size_t)(b * 256 + s0 + s) * 512 + h0 + h;
        th[s][h] = dh[gi];
        tl[s][h] = dl[gi];
    }
    __syncthreads();
#pragma unroll
    for (int i = 0; i < 16; ++i) {
        int idx = tid + i * 256;
        int h = idx >> 6, s = idx & 63;
        size_t gi = (size_t)(b * 512 + h0 + h) * 256 + s0 + s;
        dTh[gi] = th[s][h];
        dTl[gi] = tl[s][h];
    }
}

// ---------------------------------------------------------------------------
// BN stats over (b, e) for each channel c (layout y[b][CH][256])
__global__ void bn_stats_kernel(const float* __restrict__ y, int CH,
                                float* __restrict__ mean, float* __restrict__ istd)
{
    int c = blockIdx.x, t = threadIdx.x;
    float s = 0.f, ss = 0.f;
    for (int b = 0; b < Bz; ++b) {
        float v = y[((long)b * CH + c) * 256 + t];
        s += v; ss += v * v;
    }
    __shared__ float rs[256], rss[256];
    rs[t] = s; rss[t] = ss; __syncthreads();
    for (int off = 128; off > 0; off >>= 1) {
        if (t < off) { rs[t] += rs[t + off]; rss[t] += rss[t + off]; }
        __syncthreads();
    }
    if (t == 0) {
        float cnt = (float)(Bz * 256);
        float m = rs[0] / cnt;
        float var = rss[0] / cnt - m * m;
        mean[c] = m;
        istd[c] = rsqrtf(var + 1e-5f);
    }
}

// BN apply + activation. HL=1: write scaled hi/lo f16; HL=0: in-place f32.
template<int EPI, int HL>
__global__ void bn_apply_kernel(float* __restrict__ y, _Float16* __restrict__ yh,
                                _Float16* __restrict__ yl, int CH,
                                const float* __restrict__ mean, const float* __restrict__ istd,
                                const float* __restrict__ g, const float* __restrict__ be)
{
    long i = (long)blockIdx.x * 256 + threadIdx.x;
    int c = (int)((i >> 8) % CH);
    float v = (y[i] - mean[c]) * istd[c] * g[c] + be[c];
    v = (EPI == 1) ? fmaxf(v, 0.f) : tanhf(v);
    if (HL) {
        float t = v * SCL;
        _Float16 h = (_Float16)t;
        yh[i] = h;
        yl[i] = (_Float16)(t - (float)h);
    } else {
        y[i] = v;
    }
}

// ---------------------------------------------------------------------------
// Output: cosine similarity * 10
__global__ void out_kernel(const float* __restrict__ e, const float* __restrict__ Vsum,
                           const float* __restrict__ vnorm, float* __restrict__ out)
{
    int bl = blockIdx.x;
    int l = bl & (Lz - 1);
    int t = threadIdx.x;
    float ev = e[(long)bl * 256 + t];
    float vv = Vsum[l * 256 + t];
    __shared__ float rd[256], rn[256];
    rd[t] = ev * vv; rn[t] = ev * ev; __syncthreads();
    for (int off = 128; off > 0; off >>= 1) {
        if (t < off) { rd[t] += rd[t + off]; rn[t] += rn[t + off]; }
        __syncthreads();
    }
    if (t == 0) {
        float num = rd[0];
        float den = fmaxf(sqrtf(rn[0]), 1e-8f) * fmaxf(vnorm[l], 1e-8f);
        out[bl] = num / den * 10.f;
    }
}

// ---------------------------------------------------------------------------
extern "C" void kernel_launch(void* const* d_in, const int* in_sizes, int n_in,
                              void* d_out, int out_size, void* d_ws, size_t ws_size,
                              hipStream_t stream)
{
    const int*   x      = (const int*)d_in[0];
    const int*   V_idx  = (const int*)d_in[1];
    const float* emb    = (const float*)d_in[2];
    const float* w_ih_f = (const float*)d_in[3];
    const float* w_hh_f = (const float*)d_in[4];
    const float* b_ih_f = (const float*)d_in[5];
    const float* b_hh_f = (const float*)d_in[6];
    const float* w_ih_b = (const float*)d_in[7];
    const float* w_hh_b = (const float*)d_in[8];
    const float* b_ih_b = (const float*)d_in[9];
    const float* b_hh_b = (const float*)d_in[10];
    const float* w1     = (const float*)d_in[11];
    const float* b1     = (const float*)d_in[12];
    const float* w2     = (const float*)d_in[13];
    const float* b2     = (const float*)d_in[14];
    const float* g1     = (const float*)d_in[15];
    const float* be1    = (const float*)d_in[16];
    const float* g2     = (const float*)d_in[17];
    const float* be2    = (const float*)d_in[18];

    float* ws = (float*)d_ws;
    float* out = (float*)d_out;

    // ---- workspace layout (float units); total ~207 MB (round-4 proven) ----
    float*    vsum   = ws;                               // 262144
    float*    vnorm  = ws + 262144;                      // 1024
    float*    mean   = ws + 263168;                      // 1024
    float*    istd   = ws + 264192;                      // 1024
    half2_t*  wqf    = (half2_t*)(ws + 265216);          // 98304
    half2_t*  wqb    = (half2_t*)(ws + 363520);          // 98304
    _Float16* vsh    = (_Float16*)(ws + 461824);         // 131072 fl
    _Float16* vsl    = (_Float16*)(ws + 592896);         // 131072 fl
    _Float16* wihh_f = (_Float16*)(ws + 723968);         // 98304 fl
    _Float16* wihl_f = (_Float16*)(ws + 822272);         // 98304 fl
    _Float16* wihh_b = (_Float16*)(ws + 920576);         // 98304 fl
    _Float16* wihl_b = (_Float16*)(ws + 1018880);        // 98304 fl
    _Float16* w1h    = (_Float16*)(ws + 1117184);        // 65536 fl
    _Float16* w1l    = (_Float16*)(ws + 1182720);        // 65536 fl
    _Float16* w2h    = (_Float16*)(ws + 1248256);        // 65536 fl
    _Float16* w2l    = (_Float16*)(ws + 1313792);        // 65536 fl
    float*    AB     = ws + 1379328;                     // overlay arena
    _Float16* xeh    = (_Float16*)(AB + 0);              // st1-2
    _Float16* xel    = (_Float16*)(AB + 2097152);
    float*    gxf    = AB + 4194304;                     // st2-3
    float*    gxb    = AB + 16777216;
    _Float16* dh     = (_Float16*)(AB + 29360128);       // st3-4 (+dtrans)
    _Float16* dl     = (_Float16*)(AB + 33554432);
    _Float16* dTh    = (_Float16*)(AB + 0);              // dtrans-st6 (xe/gx dead)
    _Float16* dTl    = (_Float16*)(AB + 4194304);
    float*    d2pre  = AB + 8388608;                     // st4 (gx dead)
    _Float16* d2h    = (_Float16*)(AB + 12582912);       // st4-5
    _Float16* d2l    = (_Float16*)(AB + 14680064);
    _Float16* ah     = (_Float16*)(AB + 16777216);       // st5-6 (gxb/d dead)
    _Float16* al     = (_Float16*)(AB + 25165824);
    _Float16* c16    = (_Float16*)(AB + 33554432);       // st6-7 (dl dead)
    float*    epre   = AB + 0;                           // st7-8 (dT/d2 dead)

    // Stage 1: gathers + packs
    vsum_kernel<<<Lz, 256, 0, stream>>>(V_idx, emb, vsum, vsh, vsl, vnorm);
    xe_kernel<<<Bz * Sz, 256, 0, stream>>>(x, emb, xeh, xel);
    wpack_kernel<<<384, 256, 0, stream>>>(w_hh_f, w_hh_b, wqf, wqb);
    cvtsplit_kernel<<<768, 256, 0, stream>>>(w_ih_f, wihh_f, wihl_f, 196608);
    cvtsplit_kernel<<<768, 256, 0, stream>>>(w_ih_b, wihh_b, wihl_b, 196608);
    cvtsplit_kernel<<<512, 256, 0, stream>>>(w1, w1h, w1l, 131072);
    cvtsplit_kernel<<<512, 256, 0, stream>>>(w2, w2h, w2l, 131072);

    // Stage 2: gx = xe @ w_ih^T + b_ih  (M=16384, N=768, K=256), f32 out
    gemm_mfma<0, 1, 0, 1><<<dim3(6, 128, 1), 256, 0, stream>>>(
        xeh, xel, wihh_f, wihl_f, b_ih_f, gxf, nullptr, nullptr, Bz * Sz, 768, Ez, 0, 0, 0);
    gemm_mfma<0, 1, 0, 1><<<dim3(6, 128, 1), 256, 0, stream>>>(
        xeh, xel, wihh_b, wihl_b, b_ih_b, gxb, nullptr, nullptr, Bz * Sz, 768, Ez, 0, 0, 0);

    // Stage 3: GRU (hybrid LDS+stream) -> d hi/lo; transpose -> dT [B,512,256]
    gru_kernel<<<128, 512, 155136, stream>>>(gxf, gxb, wqf, wqb, b_hh_f, b_hh_b, dh, dl);
    dtrans_kernel<<<dim3(4, 8, Bz), 256, 0, stream>>>(dh, dl, dTh, dTl);

    // Stage 4: d2pre = d @ w1^T + b1 (M=16384, N=256, K=512) f32; BN1+relu -> hi/lo
    gemm_mfma<0, 1, 0, 1><<<dim3(2, 128, 1), 256, 0, stream>>>(
        dh, dl, w1h, w1l, b1, d2pre, nullptr, nullptr, Bz * Sz, Ez, 512, 0, 0, 0);
    bn_stats_kernel<<<Sz, 256, 0, stream>>>(d2pre, Sz, mean, istd);
    bn_apply_kernel<1, 1><<<Bz * Sz, 256, 0, stream>>>(d2pre, d2h, d2l, Sz, mean, istd, g1, be1);

    // Stage 5: a[b] = tanh(Vsum @ d2[b]^T)  (M=1024, N=256, K=256) -> hi/lo
    gemm_mfma<2, 0, 1, 1><<<dim3(2, 8, Bz), 256, 0, stream>>>(
        vsh, vsl, d2h, d2l, nullptr, nullptr, ah, al, Lz, Sz, Ez, 0, (long)Sz * Ez, (long)Lz * Sz);

    // Stage 6: c[b] = relu(a[b] @ dT[b]^T)  (M=1024, N=512, K=256) -> hi only
    gemm_mfma<1, 0, 2, 1><<<dim3(4, 8, Bz), 256, 0, stream>>>(
        ah, al, dTh, dTl, nullptr, nullptr, c16, nullptr, Lz, 512, Sz,
        (long)Lz * Sz, (long)512 * Sz, (long)Lz * 512);

    // Stage 7: epre = c @ w2^T + b2 (M=65536, N=256, K=512, A hi-only) f32; BN2+tanh
    gemm_mfma<0, 1, 0, 0><<<dim3(2, 512, 1), 256, 0, stream>>>(
        c16, nullptr, w2h, w2l, b2, epre, nullptr, nullptr, Bz * Lz, Ez, 512, 0, 0, 0);
    bn_stats_kernel<<<Lz, 256, 0, stream>>>(epre, Lz, mean, istd);
    bn_apply_kernel<2, 0><<<Bz * Lz, 256, 0, stream>>>(epre, nullptr, nullptr, Lz, mean, istd, g2, be2);

    // Stage 8: output
    out_kernel<<<Bz * Lz, 256, 0, stream>>>(epre, vsum, vnorm, out);
}

// Round 10
// 692.960 us; speedup vs baseline: 1.6869x; 1.1208x over previous
//
#include <hip/hip_runtime.h>
#include <hip/hip_bf16.h>

// Sizes (fixed per problem)
#define Bz 64
#define Sz 256
#define Ez 256
#define Hz 256
#define Lz 1024
#define VLz 16

// split-precision scale: x stored as hi+lo of (x*SCL); products carry SCL^2
#define SCL 64.0f
#define DESCL (1.0f / 4096.0f)

typedef _Float16 half2_t __attribute__((ext_vector_type(2)));
typedef _Float16 half4_t __attribute__((ext_vector_type(4)));
typedef _Float16 f16x8   __attribute__((ext_vector_type(8)));
typedef float    f32x4   __attribute__((ext_vector_type(4)));

__device__ inline float fdot2(half2_t a, half2_t b, float c) {
#if __has_builtin(__builtin_amdgcn_fdot2)
    return __builtin_amdgcn_fdot2(a, b, c, false);
#else
    return c + (float)a[0] * (float)b[0] + (float)a[1] * (float)b[1];
#endif
}

// async global->LDS 16B; LDS dest must be linear lane-ordered (m104/m173)
__device__ inline void stage16(_Float16* ldst, const _Float16* gsrc) {
#if __has_builtin(__builtin_amdgcn_global_load_lds)
    __builtin_amdgcn_global_load_lds(
        (const __attribute__((address_space(1))) unsigned int*)gsrc,
        (__attribute__((address_space(3))) unsigned int*)ldst, 16, 0, 0);
#else
    *(f16x8*)ldst = *(const f16x8*)gsrc;
#endif
}

// ---------------------------------------------------------------------------
// K1: Vsum[l,e] = sum_j emb[V_idx[l,j], e]; norms; hi/lo split copy
__global__ void vsum_kernel(const int* __restrict__ V_idx, const float* __restrict__ emb,
                            float* __restrict__ Vsum, _Float16* __restrict__ vsh,
                            _Float16* __restrict__ vsl, float* __restrict__ vnorm)
{
    int l = blockIdx.x, e = threadIdx.x;
    float s = 0.f;
#pragma unroll
    for (int j = 0; j < VLz; ++j) {
        int idx = V_idx[l * VLz + j];
        s += emb[(long)idx * Ez + e];
    }
    Vsum[l * Ez + e] = s;
    float t = s * SCL;
    _Float16 h = (_Float16)t;
    vsh[l * Ez + e] = h;
    vsl[l * Ez + e] = (_Float16)(t - (float)h);
    __shared__ float red[256];
    red[e] = s * s; __syncthreads();
    for (int off = 128; off > 0; off >>= 1) { if (e < off) red[e] += red[e + off]; __syncthreads(); }
    if (e == 0) vnorm[l] = sqrtf(red[0]);
}

// K2: xe gather, hi/lo
__global__ void xe_kernel(const int* __restrict__ x, const float* __restrict__ emb,
                          _Float16* __restrict__ xeh, _Float16* __restrict__ xel)
{
    int i = blockIdx.x;              // b*S+s
    int e = threadIdx.x;
    float v = emb[(long)x[i] * Ez + e] * SCL;
    _Float16 h = (_Float16)v;
    xeh[(long)i * Ez + e] = h;
    xel[(long)i * Ez + e] = (_Float16)(v - (float)h);
}

// K3: pack w_hh [768,256] fp32 -> f16x2 quad layout for the GRU (round-2/4 proven).
// out index i = ((kq*3+g)*2+p)*256 + t  holds (w[g*256+t][4kq+2p], w[g*256+t][4kq+2p+1])
__global__ void wpack_kernel(const float* __restrict__ w_f, const float* __restrict__ w_b,
                             half2_t* __restrict__ out_f, half2_t* __restrict__ out_b)
{
    int i = blockIdx.x * 256 + threadIdx.x;   // 0 .. 98303
    int t = i & 255;
    int rest = i >> 8;          // (kq*3+g)*2+p
    int p = rest & 1;
    int gq = rest >> 1;
    int g = gq % 3;
    int kq = gq / 3;
    int o = g * 256 + t;
    int k = 4 * kq + 2 * p;
    out_f[i] = half2_t{(_Float16)w_f[o * 256 + k], (_Float16)w_f[o * 256 + k + 1]};
    out_b[i] = half2_t{(_Float16)w_b[o * 256 + k], (_Float16)w_b[o * 256 + k + 1]};
}

// f32 -> scaled hi/lo f16
__global__ void cvtsplit_kernel(const float* __restrict__ in, _Float16* __restrict__ hi,
                                _Float16* __restrict__ lo, int n)
{
    int i = blockIdx.x * 256 + threadIdx.x;
    if (i < n) {
        float v = in[i] * SCL;
        _Float16 h = (_Float16)v;
        hi[i] = h;
        lo[i] = (_Float16)(v - (float)h);
    }
}

// ---------------------------------------------------------------------------
// Split-precision MFMA NT GEMM (round-4 proven): C = (1/4096)*(Ah+Al)@(Bh+Bl)^T.
// acc = Ah*Bh + Ah*Bl (+ Al*Bh if SPLIT_A). BM=BN=128, BK=32, 4 waves 2x2.
// OUTM: 0 = f32 C, 1 = scaled hi/lo f16 (Ch,Cl), 2 = scaled hi f16 only.
// bias_b: alternate bias selected when blockIdx.z==1 (merged f/b dispatches).
template<int EPI, int BIAS, int OUTM, int SPLIT_A>
__global__ __launch_bounds__(256, 2) void gemm_mfma(
    const _Float16* __restrict__ Ah, const _Float16* __restrict__ Al,
    const _Float16* __restrict__ Bh, const _Float16* __restrict__ Bl,
    const float* __restrict__ bias, const float* __restrict__ bias_b,
    float* __restrict__ C, _Float16* __restrict__ Ch, _Float16* __restrict__ Cl,
    int M, int N, int K, long sA, long sB, long sC)
{
    int bz = blockIdx.z;
    Ah += (long)bz * sA;
    if (SPLIT_A) Al += (long)bz * sA;
    Bh += (long)bz * sB;
    Bl += (long)bz * sB;
    const float* bp = BIAS ? (bz ? bias_b : bias) : nullptr;
    __shared__ __attribute__((aligned(16))) _Float16 Ash[128 * 32];
    __shared__ __attribute__((aligned(16))) _Float16 Asl[128 * 32];
    __shared__ __attribute__((aligned(16))) _Float16 Bsh[128 * 32];
    __shared__ __attribute__((aligned(16))) _Float16 Bsl[128 * 32];
    int tid = threadIdx.x;
    int lane = tid & 63;
    int wid = tid >> 6;
    int wm = wid >> 1, wn = wid & 1;
    int m0 = blockIdx.y * 128, n0 = blockIdx.x * 128;

    int srow = tid >> 2, sslot = tid & 3;
    int sw0 = sslot ^ ((srow >> 1) & 3);
    long a0 = (long)(m0 + srow) * K + sw0 * 8;
    long a1 = (long)(m0 + 64 + srow) * K + sw0 * 8;
    long b0 = (long)(n0 + srow) * K + sw0 * 8;
    long b1 = (long)(n0 + 64 + srow) * K + sw0 * 8;

    f32x4 acc[4][4] = {};
    int r16 = lane & 15, kg = lane >> 4;

    for (int k0 = 0; k0 < K; k0 += 32) {
        stage16(&Ash[tid * 8],        Ah + a0 + k0);
        stage16(&Ash[2048 + tid * 8], Ah + a1 + k0);
        if (SPLIT_A) {
            stage16(&Asl[tid * 8],        Al + a0 + k0);
            stage16(&Asl[2048 + tid * 8], Al + a1 + k0);
        }
        stage16(&Bsh[tid * 8],        Bh + b0 + k0);
        stage16(&Bsh[2048 + tid * 8], Bh + b1 + k0);
        stage16(&Bsl[tid * 8],        Bl + b0 + k0);
        stage16(&Bsl[2048 + tid * 8], Bl + b1 + k0);
        __syncthreads();
        f16x8 afh[4], afl[4], bfh[4], bfl[4];
#pragma unroll
        for (int mi = 0; mi < 4; ++mi) {
            int r = wm * 64 + mi * 16 + r16;
            int sl = kg ^ ((r >> 1) & 3);
            int off = r * 32 + sl * 8;
            afh[mi] = *(const f16x8*)&Ash[off];
            if (SPLIT_A) afl[mi] = *(const f16x8*)&Asl[off];
        }
#pragma unroll
        for (int ni = 0; ni < 4; ++ni) {
            int n = wn * 64 + ni * 16 + r16;
            int sl = kg ^ ((n >> 1) & 3);
            int off = n * 32 + sl * 8;
            bfh[ni] = *(const f16x8*)&Bsh[off];
            bfl[ni] = *(const f16x8*)&Bsl[off];
        }
#pragma unroll
        for (int mi = 0; mi < 4; ++mi)
#pragma unroll
            for (int ni = 0; ni < 4; ++ni) {
                acc[mi][ni] = __builtin_amdgcn_mfma_f32_16x16x32_f16(afh[mi], bfh[ni], acc[mi][ni], 0, 0, 0);
                acc[mi][ni] = __builtin_amdgcn_mfma_f32_16x16x32_f16(afh[mi], bfl[ni], acc[mi][ni], 0, 0, 0);
                if (SPLIT_A)
                    acc[mi][ni] = __builtin_amdgcn_mfma_f32_16x16x32_f16(afl[mi], bfh[ni], acc[mi][ni], 0, 0, 0);
            }
        __syncthreads();
    }

    long coff = (long)bz * sC;
#pragma unroll
    for (int mi = 0; mi < 4; ++mi) {
#pragma unroll
        for (int ni = 0; ni < 4; ++ni) {
            int n = n0 + wn * 64 + ni * 16 + r16;
            float bv = BIAS ? bp[n] : 0.f;
#pragma unroll
            for (int j = 0; j < 4; ++j) {
                int m = m0 + wm * 64 + mi * 16 + kg * 4 + j;
                float v = acc[mi][ni][j] * DESCL + bv;
                if (EPI == 1) v = fmaxf(v, 0.f);
                if (EPI == 2) v = tanhf(v);
                long idx = coff + (long)m * N + n;
                if (OUTM == 0) {
                    C[idx] = v;
                } else if (OUTM == 1) {
                    float t = v * SCL;
                    _Float16 h = (_Float16)t;
                    Ch[idx] = h;
                    Cl[idx] = (_Float16)(t - (float)h);
                } else {
                    Ch[idx] = (_Float16)(v * SCL);
                }
            }
        }
    }
}

// ---------------------------------------------------------------------------
// K4: GRU recurrence — round-4 exact (361us, measured AT the 35.7 TB/s aggregate
// L2 ceiling: 128 blocks x 393KB x 256 steps / 361us). One block per (dir,batch),
// 512 threads = 8 waves, k-split 2: thread (q,t). The wr[] "array" is re-streamed
// from L2 by the allocator each step — that stream IS the roofline; register
// pinning (r5), Q=1/256-cap (r6), MFMA-frag (r7), LDS-hybrid (r9) all measured
// worse. h kept f16 in LDS for dots + f32 mirror for the d hi/lo output.
__global__ __launch_bounds__(512, 2) void gru_kernel(
    const float* __restrict__ gx_f, const float* __restrict__ gx_b,
    const half2_t* __restrict__ wq_f, const half2_t* __restrict__ wq_b,
    const float* __restrict__ bhh_f, const float* __restrict__ bhh_b,
    _Float16* __restrict__ dh_out, _Float16* __restrict__ dl_out)
{
    int dir = blockIdx.x >> 6;
    int b   = blockIdx.x & 63;
    const float*   gx  = dir ? gx_b : gx_f;
    const half2_t* wq  = dir ? wq_b : wq_f;
    const float*   bhh = dir ? bhh_b : bhh_f;
    int tid = threadIdx.x;
    int t = tid & 255, q = tid >> 8;

    __shared__ __attribute__((aligned(16))) _Float16 hbuf[256];
    __shared__ float hf32[256];
    __shared__ float part[2 * 768];

    half2_t wr[192];
    const half2_t* wbase = wq + (size_t)q * 192 * 256 + t;
#pragma unroll
    for (int m = 0; m < 192; ++m) wr[m] = wbase[m << 8];

    float br = 0.f, bz = 0.f, bn = 0.f, hprev = 0.f;
    if (q == 0) {
        br = bhh[t]; bz = bhh[256 + t]; bn = bhh[512 + t];
        hbuf[t] = (_Float16)0.f;
        hf32[t] = 0.f;
    }
    __syncthreads();

    for (int step = 0; step < Sz; ++step) {
        int s = dir ? (Sz - 1 - step) : step;
        // deferred previous-step d write (overlaps dot phase)
        if (q == 1 && step > 0) {
            int sp = dir ? (Sz - step) : (step - 1);
            float hv = hf32[t] * SCL;
            _Float16 hh = (_Float16)hv;
            size_t idx = (size_t)(b * Sz + sp) * 512 + dir * 256 + t;
            dh_out[idx] = hh;
            dl_out[idx] = (_Float16)(hv - (float)hh);
        }
        const float* g = gx + (size_t)(b * Sz + s) * 768;
        float xr = 0.f, xz = 0.f, xn = 0.f;
        if (q == 0) { xr = g[t]; xz = g[256 + t]; xn = g[512 + t]; }

        float ar = 0.f, az = 0.f, an = 0.f;
        const half4_t* hp = (const half4_t*)hbuf;
#pragma unroll
        for (int jj = 0; jj < 32; ++jj) {
            half4_t hv = hp[q * 32 + jj];
            half2_t h01 = {hv[0], hv[1]};
            half2_t h23 = {hv[2], hv[3]};
            ar = fdot2(wr[jj * 6 + 0], h01, ar); ar = fdot2(wr[jj * 6 + 1], h23, ar);
            az = fdot2(wr[jj * 6 + 2], h01, az); az = fdot2(wr[jj * 6 + 3], h23, az);
            an = fdot2(wr[jj * 6 + 4], h01, an); an = fdot2(wr[jj * 6 + 5], h23, an);
        }
        part[q * 768 + t]       = ar;
        part[q * 768 + 256 + t] = az;
        part[q * 768 + 512 + t] = an;
        __syncthreads();

        if (q == 0) {
            float hr = part[t]       + part[768 + t];
            float hz = part[256 + t] + part[768 + 256 + t];
            float hn = part[512 + t] + part[768 + 512 + t];
            float r  = 1.f / (1.f + expf(-(xr + br + hr)));
            float z  = 1.f / (1.f + expf(-(xz + bz + hz)));
            float nn = tanhf(xn + r * (hn + bn));
            hprev = (1.f - z) * nn + z * hprev;
            hbuf[t] = (_Float16)hprev;
            hf32[t] = hprev;
        }
        __syncthreads();
    }
    // final step's d write
    if (q == 1) {
        int sl = dir ? 0 : (Sz - 1);
        float hv = hf32[t] * SCL;
        _Float16 hh = (_Float16)hv;
        size_t idx = (size_t)(b * Sz + sl) * 512 + dir * 256 + t;
        dh_out[idx] = hh;
        dl_out[idx] = (_Float16)(hv - (float)hh);
    }
}

// ---------------------------------------------------------------------------
// transpose d (hi,lo) [B*S][512] -> dT (hi,lo) [B][512][256]
__global__ __launch_bounds__(256) void dtrans_kernel(
    const _Float16* __restrict__ dh, const _Float16* __restrict__ dl,
    _Float16* __restrict__ dTh, _Float16* __restrict__ dTl)
{
    __shared__ _Float16 th[64][68];
    __shared__ _Float16 tl[64][68];
    int s0 = blockIdx.x << 6;
    int h0 = blockIdx.y << 6;
    int b  = blockIdx.z;
    int tid = threadIdx.x;
#pragma unroll
    for (int i = 0; i < 16; ++i) {
        int idx = tid + i * 256;
        int s = idx >> 6, h = idx & 63;
        size_t gi = (size_t)(b * 256 + s0 + s) * 512 + h0 + h;
        th[s][h] = dh[gi];
        tl[s][h] = dl[gi];
    }
    __syncthreads();
#pragma unroll
    for (int i = 0; i < 16; ++i) {
        int idx = tid + i * 256;
        int h = idx >> 6, s = idx & 63;
        size_t gi = (size_t)(b * 512 + h0 + h) * 256 + s0 + s;
        dTh[gi] = th[s][h];
        dTl[gi] = tl[s][h];
    }
}

// ---------------------------------------------------------------------------
// BN stats over (b, e) for each channel c (layout y[b][CH][256])
__global__ void bn_stats_kernel(const float* __restrict__ y, int CH,
                                float* __restrict__ mean, float* __restrict__ istd)
{
    int c = blockIdx.x, t = threadIdx.x;
    float s = 0.f, ss = 0.f;
    for (int b = 0; b < Bz; ++b) {
        float v = y[((long)b * CH + c) * 256 + t];
        s += v; ss += v * v;
    }
    __shared__ float rs[256], rss[256];
    rs[t] = s; rss[t] = ss; __syncthreads();
    for (int off = 128; off > 0; off >>= 1) {
        if (t < off) { rs[t] += rs[t + off]; rss[t] += rss[t + off]; }
        __syncthreads();
    }
    if (t == 0) {
        float cnt = (float)(Bz * 256);
        float m = rs[0] / cnt;
        float var = rss[0] / cnt - m * m;
        mean[c] = m;
        istd[c] = rsqrtf(var + 1e-5f);
    }
}

// BN1 apply + relu -> scaled hi/lo f16
__global__ void bn_apply_relu_kernel(const float* __restrict__ y,
                                     _Float16* __restrict__ yh, _Float16* __restrict__ yl,
                                     const float* __restrict__ mean, const float* __restrict__ istd,
                                     const float* __restrict__ g, const float* __restrict__ be)
{
    long i = (long)blockIdx.x * 256 + threadIdx.x;
    int c = (int)((i >> 8) % Sz);
    float v = (y[i] - mean[c]) * istd[c] * g[c] + be[c];
    v = fmaxf(v, 0.f);
    float t = v * SCL;
    _Float16 h = (_Float16)t;
    yh[i] = h;
    yl[i] = (_Float16)(t - (float)h);
}

// ---------------------------------------------------------------------------
// Fused BN2-apply + tanh + cosine-similarity output (replaces bn_apply<2> +
// out_kernel; saves a full 67MB+67MB epre round-trip and a launch).
__global__ void bn_tanh_out_kernel(const float* __restrict__ epre,
                                   const float* __restrict__ mean, const float* __restrict__ istd,
                                   const float* __restrict__ g, const float* __restrict__ be,
                                   const float* __restrict__ Vsum, const float* __restrict__ vnorm,
                                   float* __restrict__ out)
{
    int bl = blockIdx.x;               // b*Lz + l
    int l = bl & (Lz - 1);
    int t = threadIdx.x;
    float v = (epre[(long)bl * 256 + t] - mean[l]) * istd[l] * g[l] + be[l];
    float ev = tanhf(v);
    float vv = Vsum[l * 256 + t];
    __shared__ float rd[256], rn[256];
    rd[t] = ev * vv; rn[t] = ev * ev; __syncthreads();
    for (int off = 128; off > 0; off >>= 1) {
        if (t < off) { rd[t] += rd[t + off]; rn[t] += rn[t + off]; }
        __syncthreads();
    }
    if (t == 0) {
        float num = rd[0];
        float den = fmaxf(sqrtf(rn[0]), 1e-8f) * fmaxf(vnorm[l], 1e-8f);
        out[bl] = num / den * 10.f;
    }
}

// ---------------------------------------------------------------------------
extern "C" void kernel_launch(void* const* d_in, const int* in_sizes, int n_in,
                              void* d_out, int out_size, void* d_ws, size_t ws_size,
                              hipStream_t stream)
{
    const int*   x      = (const int*)d_in[0];
    const int*   V_idx  = (const int*)d_in[1];
    const float* emb    = (const float*)d_in[2];
    const float* w_ih_f = (const float*)d_in[3];
    const float* w_hh_f = (const float*)d_in[4];
    const float* b_ih_f = (const float*)d_in[5];
    const float* b_hh_f = (const float*)d_in[6];
    const float* w_ih_b = (const float*)d_in[7];
    const float* w_hh_b = (const float*)d_in[8];
    const float* b_ih_b = (const float*)d_in[9];
    const float* b_hh_b = (const float*)d_in[10];
    const float* w1     = (const float*)d_in[11];
    const float* b1     = (const float*)d_in[12];
    const float* w2     = (const float*)d_in[13];
    const float* b2     = (const float*)d_in[14];
    const float* g1     = (const float*)d_in[15];
    const float* be1    = (const float*)d_in[16];
    const float* g2     = (const float*)d_in[17];
    const float* be2    = (const float*)d_in[18];

    float* ws = (float*)d_ws;
    float* out = (float*)d_out;

    // ---- workspace layout (float units); total ~207 MB (round-4 proven) ----
    float*    vsum   = ws;                               // 262144
    float*    vnorm  = ws + 262144;                      // 1024
    float*    mean   = ws + 263168;                      // 1024
    float*    istd   = ws + 264192;                      // 1024
    half2_t*  wqf    = (half2_t*)(ws + 265216);          // 98304
    half2_t*  wqb    = (half2_t*)(ws + 363520);          // 98304
    _Float16* vsh    = (_Float16*)(ws + 461824);         // 131072 fl
    _Float16* vsl    = (_Float16*)(ws + 592896);         // 131072 fl
    _Float16* wihh_f = (_Float16*)(ws + 723968);         // 98304 fl
    _Float16* wihl_f = (_Float16*)(ws + 822272);         // 98304 fl
    _Float16* wihh_b = (_Float16*)(ws + 920576);         // 98304 fl (f->b stride 393216 halves)
    _Float16* wihl_b = (_Float16*)(ws + 1018880);        // 98304 fl
    _Float16* w1h    = (_Float16*)(ws + 1117184);        // 65536 fl
    _Float16* w1l    = (_Float16*)(ws + 1182720);        // 65536 fl
    _Float16* w2h    = (_Float16*)(ws + 1248256);        // 65536 fl
    _Float16* w2l    = (_Float16*)(ws + 1313792);        // 65536 fl
    float*    AB     = ws + 1379328;                     // overlay arena
    _Float16* xeh    = (_Float16*)(AB + 0);              // st1-2
    _Float16* xel    = (_Float16*)(AB + 2097152);
    float*    gxf    = AB + 4194304;                     // st2-3 (f->b stride 12582912 fl)
    float*    gxb    = AB + 16777216;
    _Float16* dh     = (_Float16*)(AB + 29360128);       // st3-4 (+dtrans)
    _Float16* dl     = (_Float16*)(AB + 33554432);
    _Float16* dTh    = (_Float16*)(AB + 0);              // dtrans-st6 (xe/gx dead)
    _Float16* dTl    = (_Float16*)(AB + 4194304);
    float*    d2pre  = AB + 8388608;                     // st4 (gx dead)
    _Float16* d2h    = (_Float16*)(AB + 12582912);       // st4-5
    _Float16* d2l    = (_Float16*)(AB + 14680064);
    _Float16* ah     = (_Float16*)(AB + 16777216);       // st5-6 (gxb/d dead)
    _Float16* al     = (_Float16*)(AB + 25165824);
    _Float16* c16    = (_Float16*)(AB + 33554432);       // st6-7 (dl dead)
    float*    epre   = AB + 0;                           // st7-8 (dT/d2 dead)

    // Stage 1: gathers + packs
    vsum_kernel<<<Lz, 256, 0, stream>>>(V_idx, emb, vsum, vsh, vsl, vnorm);
    xe_kernel<<<Bz * Sz, 256, 0, stream>>>(x, emb, xeh, xel);
    wpack_kernel<<<384, 256, 0, stream>>>(w_hh_f, w_hh_b, wqf, wqb);
    cvtsplit_kernel<<<768, 256, 0, stream>>>(w_ih_f, wihh_f, wihl_f, 196608);
    cvtsplit_kernel<<<768, 256, 0, stream>>>(w_ih_b, wihh_b, wihl_b, 196608);
    cvtsplit_kernel<<<512, 256, 0, stream>>>(w1, w1h, w1l, 131072);
    cvtsplit_kernel<<<512, 256, 0, stream>>>(w2, w2h, w2l, 131072);

    // Stage 2 (merged f+b via grid.z): gx = xe @ w_ih^T + b_ih  (M=16384, N=768, K=256)
    gemm_mfma<0, 1, 0, 1><<<dim3(6, 128, 2), 256, 0, stream>>>(
        xeh, xel, wihh_f, wihl_f, b_ih_f, b_ih_b, gxf, nullptr, nullptr,
        Bz * Sz, 768, Ez, 0, 393216, 12582912);

    // Stage 3: GRU (round-4 exact) -> d hi/lo; transpose -> dT [B,512,256]
    gru_kernel<<<128, 512, 0, stream>>>(gxf, gxb, wqf, wqb, b_hh_f, b_hh_b, dh, dl);
    dtrans_kernel<<<dim3(4, 8, Bz), 256, 0, stream>>>(dh, dl, dTh, dTl);

    // Stage 4: d2pre = d @ w1^T + b1 (M=16384, N=256, K=512) f32; BN1+relu -> hi/lo
    gemm_mfma<0, 1, 0, 1><<<dim3(2, 128, 1), 256, 0, stream>>>(
        dh, dl, w1h, w1l, b1, b1, d2pre, nullptr, nullptr, Bz * Sz, Ez, 512, 0, 0, 0);
    bn_stats_kernel<<<Sz, 256, 0, stream>>>(d2pre, Sz, mean, istd);
    bn_apply_relu_kernel<<<Bz * Sz, 256, 0, stream>>>(d2pre, d2h, d2l, mean, istd, g1, be1);

    // Stage 5: a[b] = tanh(Vsum @ d2[b]^T)  (M=1024, N=256, K=256) -> hi/lo
    gemm_mfma<2, 0, 1, 1><<<dim3(2, 8, Bz), 256, 0, stream>>>(
        vsh, vsl, d2h, d2l, nullptr, nullptr, nullptr, ah, al,
        Lz, Sz, Ez, 0, (long)Sz * Ez, (long)Lz * Sz);

    // Stage 6: c[b] = relu(a[b] @ dT[b]^T)  (M=1024, N=512, K=256) -> hi only
    gemm_mfma<1, 0, 2, 1><<<dim3(4, 8, Bz), 256, 0, stream>>>(
        ah, al, dTh, dTl, nullptr, nullptr, nullptr, c16, nullptr, Lz, 512, Sz,
        (long)Lz * Sz, (long)512 * Sz, (long)Lz * 512);

    // Stage 7: epre = c @ w2^T + b2 (M=65536, N=256, K=512, A hi-only) f32; BN2 stats
    gemm_mfma<0, 1, 0, 0><<<dim3(2, 512, 1), 256, 0, stream>>>(
        c16, nullptr, w2h, w2l, b2, b2, epre, nullptr, nullptr, Bz * Lz, Ez, 512, 0, 0, 0);
    bn_stats_kernel<<<Lz, 256, 0, stream>>>(epre, Lz, mean, istd);

    // Stage 8: fused BN2-apply + tanh + cosine output
    bn_tanh_out_kernel<<<Bz * Lz, 256, 0, stream>>>(epre, mean, istd, g2, be2, vsum, vnorm, out);
}